// Round 3
// baseline (598.144 us; speedup 1.0000x reference)
//
#include <hip/hip_runtime.h>
#include <cstdint>
#include <cstddef>

typedef unsigned short u16;
typedef __attribute__((ext_vector_type(8))) short short8;
typedef __attribute__((ext_vector_type(4))) float f32x4;

#define DIM 512
#define C2  256
#define HD  32
#define SCALE_Q 0.17677669529663689f

__device__ __forceinline__ float bf2f(u16 u){ return __uint_as_float(((unsigned)u) << 16); }
__device__ __forceinline__ u16 f2bf(float f){
  unsigned u = __float_as_uint(f);
  unsigned r = (u + 0x7FFFu + ((u >> 16) & 1u)) >> 16;
  return (u16)r;
}

__device__ __forceinline__ f32x4 mfma16(short8 a, short8 b, f32x4 c){
  return __builtin_amdgcn_mfma_f32_16x16x32_bf16(a, b, c, 0, 0, 0);
}

// async global->LDS, 16 bytes per lane; LDS dest must be wave-uniform base (+lane*16 implied)
__device__ __forceinline__ void gload16(const u16* g, u16* l){
  __builtin_amdgcn_global_load_lds((const __attribute__((address_space(1))) void*)g,
                                   (__attribute__((address_space(3))) void*)l, 16, 0, 0);
}

// ---------------- weight transpose + fp32->bf16: WT[n][k] = bf16(W[k][n]) ----------------
__global__ void transpose_kernel(const float* __restrict__ W, u16* __restrict__ WT, int K, int N){
  int idx = blockIdx.x * 256 + threadIdx.x;
  if (idx >= K * N) return;
  int n = idx / K;
  int k = idx - n * K;
  WT[idx] = f2bf(W[(size_t)k * N + n]);
}

// ---------------- LayerNorm over last dim (512), one wave per row; fp32 in -> bf16 out ----------------
__global__ __launch_bounds__(256) void ln_kernel(const float* __restrict__ x, const float* __restrict__ g,
                                                 const float* __restrict__ bta, u16* __restrict__ out){
  int row  = blockIdx.x * 4 + (threadIdx.x >> 6);
  int lane = threadIdx.x & 63;
  size_t base = (size_t)row * DIM + lane * 8;
  float4 v0 = *(const float4*)(x + base);
  float4 v1 = *(const float4*)(x + base + 4);
  float f[8] = {v0.x, v0.y, v0.z, v0.w, v1.x, v1.y, v1.z, v1.w};
  float s = 0.f;
#pragma unroll
  for (int j = 0; j < 8; j++) s += f[j];
#pragma unroll
  for (int m = 1; m < 64; m <<= 1) s += __shfl_xor(s, m, 64);
  float mean = s * (1.0f / DIM);
  float vs = 0.f;
#pragma unroll
  for (int j = 0; j < 8; j++){ float d = f[j] - mean; vs += d * d; }
#pragma unroll
  for (int m = 1; m < 64; m <<= 1) vs += __shfl_xor(vs, m, 64);
  float rstd = rsqrtf(vs * (1.0f / DIM) + 1e-5f);
  float4 g0 = *(const float4*)(g + lane * 8);
  float4 g1 = *(const float4*)(g + lane * 8 + 4);
  float4 b0 = *(const float4*)(bta + lane * 8);
  float4 b1 = *(const float4*)(bta + lane * 8 + 4);
  float gg[8] = {g0.x, g0.y, g0.z, g0.w, g1.x, g1.y, g1.z, g1.w};
  float bb[8] = {b0.x, b0.y, b0.z, b0.w, b1.x, b1.y, b1.z, b1.w};
  short8 o;
#pragma unroll
  for (int j = 0; j < 8; j++){
    float r = (f[j] - mean) * rstd * gg[j] + bb[j];
    o[j] = (short)f2bf(r);
  }
  *(short8*)(out + base) = o;
}

// ---------------- GEMM (m97 structure): C[M x N] = A[M x K] @ W[K x N] (+bias, +epilogue) ----------------
// A bf16 row-major (lda); WT = bf16 W-transposed [N x K] row-major.
// Tile 128x128, BK=32, 4 waves (2x2 of 64x64), linear LDS [128][32], global_load_lds width-16 staging.
// EPI: 0 = bias; 1 = bias + fp32 residual R; 2 = bias + exact gelu
template<int EPI, bool OUT_BF16>
__global__ __launch_bounds__(256) void gemm_kernel(
    const u16* __restrict__ A, int lda,
    const u16* __restrict__ WT,
    const float* __restrict__ bias,
    const float* R, int ldr,
    void* Cv, int ldc, int K)
{
  __shared__ u16 Asm[128 * 32];
  __shared__ u16 Bsm[128 * 32];
  int row0 = blockIdx.x * 128, col0 = blockIdx.y * 128;
  int tid  = threadIdx.x;
  int lane = tid & 63, wave = tid >> 6;
  int wr = wave >> 1, wc = wave & 1;
  int l16 = lane & 15, lhi = lane >> 4;

  // staging: per wave, rows [wave*32, wave*32+32) of the 128-row tile, 2 instrs of 16 rows each.
  // lane l covers row base+l/4, elems (l%4)*8 .. +8  -> matches DMA dest base + l*16 bytes.
  int srow = lane >> 2;            // 0..15
  int scol = (lane & 3) * 8;       // 0,8,16,24
  const u16* gA0 = A  + (size_t)(row0 + wave * 32 + srow) * lda + scol;
  const u16* gA1 = gA0 + 16 * (size_t)lda;
  const u16* gB0 = WT + (size_t)(col0 + wave * 32 + srow) * K + scol;
  const u16* gB1 = gB0 + 16 * (size_t)K;
  u16* lA0 = &Asm[(wave * 32) * 32];        // wave-uniform LDS bases
  u16* lA1 = &Asm[(wave * 32 + 16) * 32];
  u16* lB0 = &Bsm[(wave * 32) * 32];
  u16* lB1 = &Bsm[(wave * 32 + 16) * 32];

  f32x4 acc[4][4] = {};

  for (int k0 = 0; k0 < K; k0 += 32){
    gload16(gA0, lA0); gload16(gA1, lA1);
    gload16(gB0, lB0); gload16(gB1, lB1);
    gA0 += 32; gA1 += 32; gB0 += 32; gB1 += 32;
    __syncthreads();
    short8 af[4], bfr[4];
#pragma unroll
    for (int m = 0; m < 4; m++) af[m]  = *(const short8*)&Asm[(wr * 64 + m * 16 + l16) * 32 + lhi * 8];
#pragma unroll
    for (int n = 0; n < 4; n++) bfr[n] = *(const short8*)&Bsm[(wc * 64 + n * 16 + l16) * 32 + lhi * 8];
#pragma unroll
    for (int m = 0; m < 4; m++)
#pragma unroll
      for (int n = 0; n < 4; n++)
        acc[m][n] = mfma16(af[m], bfr[n], acc[m][n]);
    __syncthreads();
  }

#pragma unroll
  for (int m = 0; m < 4; m++){
#pragma unroll
    for (int n = 0; n < 4; n++){
      int c = col0 + wc * 64 + n * 16 + l16;
      float bb = bias[c];
#pragma unroll
      for (int i = 0; i < 4; i++){
        int r = row0 + wr * 64 + m * 16 + lhi * 4 + i;
        float v = acc[m][n][i] + bb;
        if constexpr (EPI == 1) v += R[(size_t)r * ldr + c];
        if constexpr (EPI == 2) v = 0.5f * v * (1.0f + erff(v * 0.70710678118654752f));
        if constexpr (OUT_BF16) ((u16*)Cv)[(size_t)r * ldc + c] = f2bf(v);
        else                    ((float*)Cv)[(size_t)r * ldc + c] = v;
      }
    }
  }
}

// ---------------- windowed attention + LePE, one wave per (window, head) ----------------
__global__ __launch_bounds__(64) void attn_kernel(
    const u16* __restrict__ qkv, const float* __restrict__ lw,
    const float* __restrict__ lb, u16* __restrict__ out)
{
  __shared__ float Ks[64][33];
  __shared__ float Vs[64][33];
  __shared__ float Wle[32][9];
  __shared__ float Lb[32];
  int head = blockIdx.x & 7, win = blockIdx.x >> 3;
  int wx = win & 7, wy = (win >> 3) & 7, b = win >> 6;
  int l  = threadIdx.x;           // query pixel in window
  int py = l >> 3, px = l & 7;
  size_t t = (size_t)b * 4096 + (size_t)(wy * 8 + py) * 64 + (wx * 8 + px);
  const u16* base = qkv + t * 768 + head * HD;

  float q[32];
#pragma unroll
  for (int j = 0; j < 32; j += 8){
    short8 vq = *(const short8*)(base + j);
    short8 vk = *(const short8*)(base + 256 + j);
    short8 vv = *(const short8*)(base + 512 + j);
#pragma unroll
    for (int e = 0; e < 8; e++){
      q[j + e]     = bf2f((u16)vq[e]) * SCALE_Q;
      Ks[l][j + e] = bf2f((u16)vk[e]);
      Vs[l][j + e] = bf2f((u16)vv[e]);
    }
  }
  for (int i = l; i < 288; i += 64) Wle[i / 9][i % 9] = lw[(head * 32 + i / 9) * 9 + (i % 9)];
  if (l < 32) Lb[l] = lb[head * 32 + l];
  __syncthreads();

  float sc[64];
  float mx = -1e30f;
#pragma unroll
  for (int k = 0; k < 64; k++){
    float s = 0.f;
#pragma unroll
    for (int d = 0; d < 32; d++) s += q[d] * Ks[k][d];
    sc[k] = s; mx = fmaxf(mx, s);
  }
  float sum = 0.f;
#pragma unroll
  for (int k = 0; k < 64; k++){ float e = __expf(sc[k] - mx); sc[k] = e; sum += e; }
  float inv = 1.0f / sum;
  float o[32];
#pragma unroll
  for (int d = 0; d < 32; d++) o[d] = 0.f;
#pragma unroll
  for (int k = 0; k < 64; k++){
    float p = sc[k] * inv;
#pragma unroll
    for (int d = 0; d < 32; d++) o[d] += p * Vs[k][d];
  }
  // LePE: depthwise 3x3 over the 8x8 window (zero pad at window edges)
#pragma unroll
  for (int ky = 0; ky < 3; ky++){
    int yy = py + ky - 1;
    if (yy < 0 || yy >= 8) continue;
#pragma unroll
    for (int kx = 0; kx < 3; kx++){
      int xx = px + kx - 1;
      if (xx < 0 || xx >= 8) continue;
      int kp = yy * 8 + xx;
#pragma unroll
      for (int d = 0; d < 32; d++) o[d] += Wle[d][ky * 3 + kx] * Vs[kp][d];
    }
  }
  u16* op = out + t * DIM + head * HD;
#pragma unroll
  for (int d = 0; d < 32; d++) op[d] = f2bf(o[d] + Lb[d]);
}

// ---------------- full-image depthwise 3x3 on img[..., 256:], thread = channel ----------------
__global__ __launch_bounds__(256) void convloc_kernel(const u16* __restrict__ img,
    const float* __restrict__ w, u16* __restrict__ out){
  int c  = threadIdx.x;
  int pg = blockIdx.x;            // 2048 groups of 16 pixels
  int b  = pg >> 8;
  int p0 = (pg & 255) * 16;
  float wt[9];
#pragma unroll
  for (int i = 0; i < 9; i++) wt[i] = w[c * 9 + i];
  for (int pi = 0; pi < 16; pi++){
    int p = p0 + pi;
    int y = p >> 6, x = p & 63;
    float acc = 0.f;
#pragma unroll
    for (int ky = 0; ky < 3; ky++){
      int yy = y + ky - 1;
      if (yy < 0 || yy >= 64) continue;
#pragma unroll
      for (int kx = 0; kx < 3; kx++){
        int xx = x + kx - 1;
        if (xx < 0 || xx >= 64) continue;
        acc += wt[ky * 3 + kx] * bf2f(img[((size_t)b * 4096 + yy * 64 + xx) * DIM + C2 + c]);
      }
    }
    out[((size_t)b * 4096 + p) * DIM + C2 + c] = f2bf(acc);
  }
}

extern "C" void kernel_launch(void* const* d_in, const int* in_sizes, int n_in,
                              void* d_out, int out_size, void* d_ws, size_t ws_size,
                              hipStream_t stream){
  const float* x      = (const float*)d_in[0];
  const float* n1g    = (const float*)d_in[1];
  const float* n1b    = (const float*)d_in[2];
  const float* qkv_w  = (const float*)d_in[3];
  const float* qkv_b  = (const float*)d_in[4];
  const float* lepe_w = (const float*)d_in[5];
  const float* lepe_b = (const float*)d_in[6];
  const float* conv_w = (const float*)d_in[7];
  const float* proj_w = (const float*)d_in[8];
  const float* proj_b = (const float*)d_in[9];
  const float* n2g    = (const float*)d_in[10];
  const float* n2b    = (const float*)d_in[11];
  const float* fc1_w  = (const float*)d_in[12];
  const float* fc1_b  = (const float*)d_in[13];
  const float* fc2_w  = (const float*)d_in[14];
  const float* fc2_b  = (const float*)d_in[15];
  float* out = (float*)d_out;

  char* ws = (char*)d_ws;
  // ws layout (bytes):
  //   img    bf16 [0,        33554432)
  //   qkvb   bf16 [33554432, 83886080)
  //   localb bf16 [83886080, 117440512)
  //   y      bf16 [0, 33554432)          (reuses img; img dead after convloc)
  //   h      bf16 [33554432, 167772160)  (reuses qkvb+localb; dead after proj)
  //   weights     [167772160, ~172.9M)
  // xa (fp32, 64MB) lives in d_out; fully rewritten by proj before any read,
  // fc2 does an element-bijective in-place out = xa + fc2(h).
  u16* img     = (u16*)(ws + 0);
  u16* qkvb    = (u16*)(ws + 33554432ull);
  u16* localb  = (u16*)(ws + 83886080ull);
  u16* y       = (u16*)(ws + 0);
  u16* h       = (u16*)(ws + 33554432ull);
  u16* qkv_wT  = (u16*)(ws + 167772160ull);
  u16* proj_wT = (u16*)(ws + 167772160ull + 393216ull);
  u16* fc1_wT  = (u16*)(ws + 167772160ull + 393216ull + 524288ull);
  u16* fc2_wT  = (u16*)(ws + 167772160ull + 393216ull + 524288ull + 2097152ull);
  float* xa    = (float*)d_out;

  transpose_kernel<<<768, 256, 0, stream>>>(qkv_w, qkv_wT, 256, 768);
  transpose_kernel<<<1024, 256, 0, stream>>>(proj_w, proj_wT, 512, 512);
  transpose_kernel<<<4096, 256, 0, stream>>>(fc1_w, fc1_wT, 512, 2048);
  transpose_kernel<<<4096, 256, 0, stream>>>(fc2_w, fc2_wT, 2048, 512);

  ln_kernel<<<8192, 256, 0, stream>>>(x, n1g, n1b, img);

  dim3 gq(256, 6);
  gemm_kernel<0, true><<<gq, 256, 0, stream>>>(img, DIM, qkv_wT, qkv_b, nullptr, 0, qkvb, 768, 256);

  attn_kernel<<<4096, 64, 0, stream>>>(qkvb, lepe_w, lepe_b, localb);
  convloc_kernel<<<2048, 256, 0, stream>>>(img, conv_w, localb);

  dim3 gp(256, 4);
  gemm_kernel<1, false><<<gp, 256, 0, stream>>>(localb, DIM, proj_wT, proj_b, x, DIM, xa, DIM, 512);

  ln_kernel<<<8192, 256, 0, stream>>>(xa, n2g, n2b, y);

  dim3 g1(256, 16);
  gemm_kernel<2, true><<<g1, 256, 0, stream>>>(y, DIM, fc1_wT, fc1_b, nullptr, 0, h, 2048, 512);

  dim3 g2(256, 4);
  gemm_kernel<1, false><<<g2, 256, 0, stream>>>(h, 2048, fc2_wT, fc2_b, xa, DIM, out, DIM, 2048);
}

// Round 4
// 562.086 us; speedup vs baseline: 1.0641x; 1.0641x over previous
//
#include <hip/hip_runtime.h>
#include <cstdint>
#include <cstddef>

typedef unsigned short u16;
typedef __attribute__((ext_vector_type(8))) short short8;
typedef __attribute__((ext_vector_type(4))) float f32x4;

#define DIM 512
#define C2  256
#define HD  32
#define SCALE_Q 0.17677669529663689f

__device__ __forceinline__ float bf2f(u16 u){ return __uint_as_float(((unsigned)u) << 16); }
__device__ __forceinline__ u16 f2bf(float f){
  unsigned u = __float_as_uint(f);
  unsigned r = (u + 0x7FFFu + ((u >> 16) & 1u)) >> 16;
  return (u16)r;
}

__device__ __forceinline__ f32x4 mfma16(short8 a, short8 b, f32x4 c){
  return __builtin_amdgcn_mfma_f32_16x16x32_bf16(a, b, c, 0, 0, 0);
}

// async global->LDS, 16 bytes per lane; LDS dest is wave-uniform base (+lane*16 implied)
__device__ __forceinline__ void gload16(const u16* g, u16* l){
  __builtin_amdgcn_global_load_lds((const __attribute__((address_space(1))) void*)g,
                                   (__attribute__((address_space(3))) void*)l, 16, 0, 0);
}

// fast gelu (tanh form, hardware exp); |err| vs exact erf-gelu < 3e-3 absolute
__device__ __forceinline__ float gelu_f(float v){
  float z = 0.7978845608028654f * (v + 0.044715f * v * v * v);
  z = fminf(10.0f, fmaxf(-10.0f, z));
  float e = __expf(2.0f * z);
  float th = (e - 1.0f) / (e + 1.0f);
  return 0.5f * v * (1.0f + th);
}

// ---------------- weight transpose + fp32->bf16: WT[n][k] = bf16(W[k][n]) ----------------
__global__ void transpose_kernel(const float* __restrict__ W, u16* __restrict__ WT, int K, int N){
  int idx = blockIdx.x * 256 + threadIdx.x;
  if (idx >= K * N) return;
  int n = idx / K;
  int k = idx - n * K;
  WT[idx] = f2bf(W[(size_t)k * N + n]);
}

// ---------------- LayerNorm over last dim (512), one wave per row; fp32 in -> bf16 out ----------------
__global__ __launch_bounds__(256) void ln_kernel(const float* __restrict__ x, const float* __restrict__ g,
                                                 const float* __restrict__ bta, u16* __restrict__ out){
  int row  = blockIdx.x * 4 + (threadIdx.x >> 6);
  int lane = threadIdx.x & 63;
  size_t base = (size_t)row * DIM + lane * 8;
  float4 v0 = *(const float4*)(x + base);
  float4 v1 = *(const float4*)(x + base + 4);
  float f[8] = {v0.x, v0.y, v0.z, v0.w, v1.x, v1.y, v1.z, v1.w};
  float s = 0.f;
#pragma unroll
  for (int j = 0; j < 8; j++) s += f[j];
#pragma unroll
  for (int m = 1; m < 64; m <<= 1) s += __shfl_xor(s, m, 64);
  float mean = s * (1.0f / DIM);
  float vs = 0.f;
#pragma unroll
  for (int j = 0; j < 8; j++){ float d = f[j] - mean; vs += d * d; }
#pragma unroll
  for (int m = 1; m < 64; m <<= 1) vs += __shfl_xor(vs, m, 64);
  float rstd = rsqrtf(vs * (1.0f / DIM) + 1e-5f);
  float4 g0 = *(const float4*)(g + lane * 8);
  float4 g1 = *(const float4*)(g + lane * 8 + 4);
  float4 b0 = *(const float4*)(bta + lane * 8);
  float4 b1 = *(const float4*)(bta + lane * 8 + 4);
  float gg[8] = {g0.x, g0.y, g0.z, g0.w, g1.x, g1.y, g1.z, g1.w};
  float bb[8] = {b0.x, b0.y, b0.z, b0.w, b1.x, b1.y, b1.z, b1.w};
  short8 o;
#pragma unroll
  for (int j = 0; j < 8; j++){
    float r = (f[j] - mean) * rstd * gg[j] + bb[j];
    o[j] = (short)f2bf(r);
  }
  *(short8*)(out + base) = o;
}

// ---------------- GEMM, 2-phase double-buffered (T3-minimum recipe) ----------------
// C[M x N] = A[M x K] @ W[K x N] (+bias, +epilogue)
// A bf16 row-major (lda); WT = bf16 W-transposed [N x K] row-major.
// Tile 128x128, BK=32, 4 waves (2x2 of 64x64), linear LDS [2][128][32], global_load_lds staging.
// Grid: x = col-blocks (fast -> A-tile reuse temporally close), y = row-blocks.
// EPI: 0 = bias; 1 = bias + fp32 residual R; 2 = bias + gelu
template<int EPI, bool OUT_BF16>
__global__ __launch_bounds__(256) void gemm_kernel(
    const u16* __restrict__ A, int lda,
    const u16* __restrict__ WT,
    const float* __restrict__ bias,
    const float* R, int ldr,
    void* Cv, int ldc, int K)
{
  __shared__ u16 Asm[2][128 * 32];
  __shared__ u16 Bsm[2][128 * 32];
  int col0 = blockIdx.x * 128, row0 = blockIdx.y * 128;
  int tid  = threadIdx.x;
  int lane = tid & 63, wave = tid >> 6;
  int wr = wave >> 1, wc = wave & 1;
  int l16 = lane & 15, lhi = lane >> 4;

  // staging: per wave, rows [wave*32, wave*32+32), 2 DMA instrs of 16 rows each.
  // lane l covers row base+l/4, elems (l%4)*8..+8 -> DMA dest base + l*16 bytes.
  int srow = lane >> 2;            // 0..15
  int scol = (lane & 3) * 8;       // 0,8,16,24
  const u16* gA0 = A  + (size_t)(row0 + wave * 32 + srow) * lda + scol;
  const u16* gA1 = gA0 + 16 * (size_t)lda;
  const u16* gB0 = WT + (size_t)(col0 + wave * 32 + srow) * K + scol;
  const u16* gB1 = gB0 + 16 * (size_t)K;
  int lb0 = (wave * 32) * 32;      // wave-uniform LDS elem offsets
  int lb1 = (wave * 32 + 16) * 32;

  int NT = K >> 5;
  // prologue: stage tile 0 into buf 0
  gload16(gA0, &Asm[0][lb0]); gload16(gA1, &Asm[0][lb1]);
  gload16(gB0, &Bsm[0][lb0]); gload16(gB1, &Bsm[0][lb1]);
  __syncthreads();

  f32x4 acc[4][4] = {};
  int cur = 0;
  for (int t = 0; t < NT; t++){
    if (t + 1 < NT){               // issue next-tile loads BEFORE compute
      int nb = cur ^ 1;
      int off = (t + 1) * 32;
      gload16(gA0 + off, &Asm[nb][lb0]); gload16(gA1 + off, &Asm[nb][lb1]);
      gload16(gB0 + off, &Bsm[nb][lb0]); gload16(gB1 + off, &Bsm[nb][lb1]);
    }
    short8 af[4], bfr[4];
#pragma unroll
    for (int m = 0; m < 4; m++) af[m]  = *(const short8*)&Asm[cur][(wr * 64 + m * 16 + l16) * 32 + lhi * 8];
#pragma unroll
    for (int n = 0; n < 4; n++) bfr[n] = *(const short8*)&Bsm[cur][(wc * 64 + n * 16 + l16) * 32 + lhi * 8];
#pragma unroll
    for (int m = 0; m < 4; m++)
#pragma unroll
      for (int n = 0; n < 4; n++)
        acc[m][n] = mfma16(af[m], bfr[n], acc[m][n]);
    __syncthreads();               // implicit vmcnt(0): next tile landed; buf swap safe
    cur ^= 1;
  }

#pragma unroll
  for (int m = 0; m < 4; m++){
#pragma unroll
    for (int n = 0; n < 4; n++){
      int c = col0 + wc * 64 + n * 16 + l16;
      float bb = bias[c];
#pragma unroll
      for (int i = 0; i < 4; i++){
        int r = row0 + wr * 64 + m * 16 + lhi * 4 + i;
        float v = acc[m][n][i] + bb;
        if constexpr (EPI == 1) v += R[(size_t)r * ldr + c];
        if constexpr (EPI == 2) v = gelu_f(v);
        if constexpr (OUT_BF16) ((u16*)Cv)[(size_t)r * ldc + c] = f2bf(v);
        else                    ((float*)Cv)[(size_t)r * ldc + c] = v;
      }
    }
  }
}

// ---------------- windowed attention + LePE, one wave per (window, head) ----------------
__global__ __launch_bounds__(64) void attn_kernel(
    const u16* __restrict__ qkv, const float* __restrict__ lw,
    const float* __restrict__ lb, u16* __restrict__ out)
{
  __shared__ float Ks[64][33];
  __shared__ float Vs[64][33];
  __shared__ float Wle[32][9];
  __shared__ float Lb[32];
  int head = blockIdx.x & 7, win = blockIdx.x >> 3;
  int wx = win & 7, wy = (win >> 3) & 7, b = win >> 6;
  int l  = threadIdx.x;           // query pixel in window
  int py = l >> 3, px = l & 7;
  size_t t = (size_t)b * 4096 + (size_t)(wy * 8 + py) * 64 + (wx * 8 + px);
  const u16* base = qkv + t * 768 + head * HD;

  float q[32];
#pragma unroll
  for (int j = 0; j < 32; j += 8){
    short8 vq = *(const short8*)(base + j);
    short8 vk = *(const short8*)(base + 256 + j);
    short8 vv = *(const short8*)(base + 512 + j);
#pragma unroll
    for (int e = 0; e < 8; e++){
      q[j + e]     = bf2f((u16)vq[e]) * SCALE_Q;
      Ks[l][j + e] = bf2f((u16)vk[e]);
      Vs[l][j + e] = bf2f((u16)vv[e]);
    }
  }
  for (int i = l; i < 288; i += 64) Wle[i / 9][i % 9] = lw[(head * 32 + i / 9) * 9 + (i % 9)];
  if (l < 32) Lb[l] = lb[head * 32 + l];
  __syncthreads();

  float sc[64];
  float mx = -1e30f;
#pragma unroll
  for (int k = 0; k < 64; k++){
    float s = 0.f;
#pragma unroll
    for (int d = 0; d < 32; d++) s += q[d] * Ks[k][d];
    sc[k] = s; mx = fmaxf(mx, s);
  }
  float sum = 0.f;
#pragma unroll
  for (int k = 0; k < 64; k++){ float e = __expf(sc[k] - mx); sc[k] = e; sum += e; }
  float inv = 1.0f / sum;
  float o[32];
#pragma unroll
  for (int d = 0; d < 32; d++) o[d] = 0.f;
#pragma unroll
  for (int k = 0; k < 64; k++){
    float p = sc[k] * inv;
#pragma unroll
    for (int d = 0; d < 32; d++) o[d] += p * Vs[k][d];
  }
  // LePE: depthwise 3x3 over the 8x8 window (zero pad at window edges)
#pragma unroll
  for (int ky = 0; ky < 3; ky++){
    int yy = py + ky - 1;
    if (yy < 0 || yy >= 8) continue;
#pragma unroll
    for (int kx = 0; kx < 3; kx++){
      int xx = px + kx - 1;
      if (xx < 0 || xx >= 8) continue;
      int kp = yy * 8 + xx;
#pragma unroll
      for (int d = 0; d < 32; d++) o[d] += Wle[d][ky * 3 + kx] * Vs[kp][d];
    }
  }
  u16* op = out + t * DIM + head * HD;
#pragma unroll
  for (int d = 0; d < 32; d++) op[d] = f2bf(o[d] + Lb[d]);
}

// ---------------- full-image depthwise 3x3 on img[..., 256:], thread = channel ----------------
__global__ __launch_bounds__(256) void convloc_kernel(const u16* __restrict__ img,
    const float* __restrict__ w, u16* __restrict__ out){
  int c  = threadIdx.x;
  int pg = blockIdx.x;            // 2048 groups of 16 pixels
  int b  = pg >> 8;
  int p0 = (pg & 255) * 16;
  float wt[9];
#pragma unroll
  for (int i = 0; i < 9; i++) wt[i] = w[c * 9 + i];
  for (int pi = 0; pi < 16; pi++){
    int p = p0 + pi;
    int y = p >> 6, x = p & 63;
    float acc = 0.f;
#pragma unroll
    for (int ky = 0; ky < 3; ky++){
      int yy = y + ky - 1;
      if (yy < 0 || yy >= 64) continue;
#pragma unroll
      for (int kx = 0; kx < 3; kx++){
        int xx = x + kx - 1;
        if (xx < 0 || xx >= 64) continue;
        acc += wt[ky * 3 + kx] * bf2f(img[((size_t)b * 4096 + yy * 64 + xx) * DIM + C2 + c]);
      }
    }
    out[((size_t)b * 4096 + p) * DIM + C2 + c] = f2bf(acc);
  }
}

extern "C" void kernel_launch(void* const* d_in, const int* in_sizes, int n_in,
                              void* d_out, int out_size, void* d_ws, size_t ws_size,
                              hipStream_t stream){
  const float* x      = (const float*)d_in[0];
  const float* n1g    = (const float*)d_in[1];
  const float* n1b    = (const float*)d_in[2];
  const float* qkv_w  = (const float*)d_in[3];
  const float* qkv_b  = (const float*)d_in[4];
  const float* lepe_w = (const float*)d_in[5];
  const float* lepe_b = (const float*)d_in[6];
  const float* conv_w = (const float*)d_in[7];
  const float* proj_w = (const float*)d_in[8];
  const float* proj_b = (const float*)d_in[9];
  const float* n2g    = (const float*)d_in[10];
  const float* n2b    = (const float*)d_in[11];
  const float* fc1_w  = (const float*)d_in[12];
  const float* fc1_b  = (const float*)d_in[13];
  const float* fc2_w  = (const float*)d_in[14];
  const float* fc2_b  = (const float*)d_in[15];
  float* out = (float*)d_out;

  char* ws = (char*)d_ws;
  u16* img     = (u16*)(ws + 0);
  u16* qkvb    = (u16*)(ws + 33554432ull);
  u16* localb  = (u16*)(ws + 83886080ull);
  u16* y       = (u16*)(ws + 0);
  u16* h       = (u16*)(ws + 33554432ull);
  u16* qkv_wT  = (u16*)(ws + 167772160ull);
  u16* proj_wT = (u16*)(ws + 167772160ull + 393216ull);
  u16* fc1_wT  = (u16*)(ws + 167772160ull + 393216ull + 524288ull);
  u16* fc2_wT  = (u16*)(ws + 167772160ull + 393216ull + 524288ull + 2097152ull);
  float* xa    = (float*)d_out;

  transpose_kernel<<<768, 256, 0, stream>>>(qkv_w, qkv_wT, 256, 768);
  transpose_kernel<<<1024, 256, 0, stream>>>(proj_w, proj_wT, 512, 512);
  transpose_kernel<<<4096, 256, 0, stream>>>(fc1_w, fc1_wT, 512, 2048);
  transpose_kernel<<<4096, 256, 0, stream>>>(fc2_w, fc2_wT, 2048, 512);

  ln_kernel<<<8192, 256, 0, stream>>>(x, n1g, n1b, img);

  dim3 gq(6, 256);   // x = col-blocks, y = row-blocks
  gemm_kernel<0, true><<<gq, 256, 0, stream>>>(img, DIM, qkv_wT, qkv_b, nullptr, 0, qkvb, 768, 256);

  attn_kernel<<<4096, 64, 0, stream>>>(qkvb, lepe_w, lepe_b, localb);
  convloc_kernel<<<2048, 256, 0, stream>>>(img, conv_w, localb);

  dim3 gp(4, 256);
  gemm_kernel<1, false><<<gp, 256, 0, stream>>>(localb, DIM, proj_wT, proj_b, x, DIM, xa, DIM, 512);

  ln_kernel<<<8192, 256, 0, stream>>>(xa, n2g, n2b, y);

  dim3 g1(16, 256);
  gemm_kernel<2, true><<<g1, 256, 0, stream>>>(y, DIM, fc1_wT, fc1_b, nullptr, 0, h, 2048, 512);

  dim3 g2(4, 256);
  gemm_kernel<1, false><<<g2, 256, 0, stream>>>(h, 2048, fc2_wT, fc2_b, xa, DIM, out, DIM, 2048);
}

// Round 5
// 540.952 us; speedup vs baseline: 1.1057x; 1.0391x over previous
//
#include <hip/hip_runtime.h>
#include <cstdint>
#include <cstddef>

typedef unsigned short u16;
typedef __attribute__((ext_vector_type(8))) short short8;
typedef __attribute__((ext_vector_type(4))) float f32x4;

#define DIM 512
#define C2  256
#define HD  32
#define SCALE_Q 0.17677669529663689f

__device__ __forceinline__ float bf2f(u16 u){ return __uint_as_float(((unsigned)u) << 16); }
__device__ __forceinline__ u16 f2bf(float f){
  unsigned u = __float_as_uint(f);
  unsigned r = (u + 0x7FFFu + ((u >> 16) & 1u)) >> 16;
  return (u16)r;
}

__device__ __forceinline__ f32x4 mfma16(short8 a, short8 b, f32x4 c){
  return __builtin_amdgcn_mfma_f32_16x16x32_bf16(a, b, c, 0, 0, 0);
}

// async global->LDS, 16 bytes per lane; LDS dest is wave-uniform base (+lane*16 implied)
__device__ __forceinline__ void gload16(const u16* g, u16* l){
  __builtin_amdgcn_global_load_lds((const __attribute__((address_space(1))) void*)g,
                                   (__attribute__((address_space(3))) void*)l, 16, 0, 0);
}

// fast gelu (tanh form, hardware exp); |err| vs exact erf-gelu < 3e-3 absolute
__device__ __forceinline__ float gelu_f(float v){
  float z = 0.7978845608028654f * (v + 0.044715f * v * v * v);
  z = fminf(10.0f, fmaxf(-10.0f, z));
  float e = __expf(2.0f * z);
  float th = (e - 1.0f) / (e + 1.0f);
  return 0.5f * v * (1.0f + th);
}

// ---------------- weight transpose + fp32->bf16: WT[n][k] = bf16(W[k][n]) ----------------
__global__ void transpose_kernel(const float* __restrict__ W, u16* __restrict__ WT, int K, int N){
  int idx = blockIdx.x * 256 + threadIdx.x;
  if (idx >= K * N) return;
  int n = idx / K;
  int k = idx - n * K;
  WT[idx] = f2bf(W[(size_t)k * N + n]);
}

// ---------------- LayerNorm over last dim (512), one wave per row; fp32 in -> bf16 out ----------------
__global__ __launch_bounds__(256) void ln_kernel(const float* __restrict__ x, const float* __restrict__ g,
                                                 const float* __restrict__ bta, u16* __restrict__ out){
  int row  = blockIdx.x * 4 + (threadIdx.x >> 6);
  int lane = threadIdx.x & 63;
  size_t base = (size_t)row * DIM + lane * 8;
  float4 v0 = *(const float4*)(x + base);
  float4 v1 = *(const float4*)(x + base + 4);
  float f[8] = {v0.x, v0.y, v0.z, v0.w, v1.x, v1.y, v1.z, v1.w};
  float s = 0.f;
#pragma unroll
  for (int j = 0; j < 8; j++) s += f[j];
#pragma unroll
  for (int m = 1; m < 64; m <<= 1) s += __shfl_xor(s, m, 64);
  float mean = s * (1.0f / DIM);
  float vs = 0.f;
#pragma unroll
  for (int j = 0; j < 8; j++){ float d = f[j] - mean; vs += d * d; }
#pragma unroll
  for (int m = 1; m < 64; m <<= 1) vs += __shfl_xor(vs, m, 64);
  float rstd = rsqrtf(vs * (1.0f / DIM) + 1e-5f);
  float4 g0 = *(const float4*)(g + lane * 8);
  float4 g1 = *(const float4*)(g + lane * 8 + 4);
  float4 b0 = *(const float4*)(bta + lane * 8);
  float4 b1 = *(const float4*)(bta + lane * 8 + 4);
  float gg[8] = {g0.x, g0.y, g0.z, g0.w, g1.x, g1.y, g1.z, g1.w};
  float bb[8] = {b0.x, b0.y, b0.z, b0.w, b1.x, b1.y, b1.z, b1.w};
  short8 o;
#pragma unroll
  for (int j = 0; j < 8; j++){
    float r = (f[j] - mean) * rstd * gg[j] + bb[j];
    o[j] = (short)f2bf(r);
  }
  *(short8*)(out + base) = o;
}

// ---------------- GEMM, 256x256 8-phase schedule (T2+T3+T4+T5) ----------------
// C[M x N] = A[M x K] @ W[K x N] (+bias, +epilogue)
// A bf16 row-major (lda); WT = bf16 W-transposed [N x K] row-major. K multiple of 128.
// 8 waves (2M x 4N), per-wave C = 128x64. BK=64 split into two K-halves (kh) of 32.
// LDS: [2 dbuf][2 kh][256 rows][32 cols] per matrix = 64 KB each, 128 KB total.
// Staging: global_load_lds w16, linear LDS dest + inverse-swizzled global source;
// reads use slot = lhi ^ ((row>>1)&3)  (bank-conflict-free, rule #21 both-sides).
// Schedule per tile t: P1(kh0,qm0)+stageA(t+1,kh1)  P2(kh0,qm1)+stageB(t+1,kh1)
//                      P3(kh1,qm0)+stageA(t+2,kh0)  P4(kh1,qm1)+stageB(t+2,kh0)
//                      then s_waitcnt vmcnt(4) + s_barrier (t+2's kh0 pair stays in flight).
// Safety: each staged region's last read is >=1 closing-barrier before the stage issue.
template<int EPI, bool OUT_BF16>
__global__ __launch_bounds__(512, 2) void gemm8_kernel(
    const u16* __restrict__ A, int lda,
    const u16* __restrict__ WT,
    const float* __restrict__ bias,
    const float* R, int ldr,
    void* Cv, int ldc, int K)
{
  __shared__ u16 Al[2][2][256 * 32];
  __shared__ u16 Bl[2][2][256 * 32];
  const int tid = threadIdx.x;
  const int l   = tid & 63;
  const int w   = tid >> 6;        // wave 0..7
  const int wr  = w >> 2;          // M half
  const int wc  = w & 3;           // N quarter
  const int l16 = l & 15, lhi = l >> 4;
  const int col0 = blockIdx.x * 256, row0 = blockIdx.y * 256;
  const int NT = K >> 6;

  // per-lane staging source: lane covers LDS row (w*16 + l/4), slot (l&3).
  // source col-group = slot ^ ((row>>1)&3) = (l&3) ^ ((l>>3)&3)  [row parity bits are lane-only]
  const int srow = w * 16 + (l >> 2);
  const int cs   = (((l & 3) ^ ((l >> 3) & 3)) * 8);
  const u16* pA = A  + (size_t)(row0 + srow) * lda + cs;
  const u16* pB = WT + (size_t)(col0 + srow) * K  + cs;
  const size_t a128 = (size_t)128 * lda, b128 = (size_t)128 * K;

  auto stageA = [&](int tt, int hh){
    if (tt < NT){
      size_t go = (size_t)tt * 64 + (size_t)hh * 32;
      gload16(pA + go,        &Al[tt & 1][hh][(w * 16) * 32]);
      gload16(pA + a128 + go, &Al[tt & 1][hh][(128 + w * 16) * 32]);
    }
  };
  auto stageB = [&](int tt, int hh){
    if (tt < NT){
      size_t go = (size_t)tt * 64 + (size_t)hh * 32;
      gload16(pB + go,        &Bl[tt & 1][hh][(w * 16) * 32]);
      gload16(pB + b128 + go, &Bl[tt & 1][hh][(128 + w * 16) * 32]);
    }
  };

  // per-lane read offset within a [256][32] region (u16 units), slot-swizzled
  const int rdo = l16 * 32 + (lhi ^ ((l16 >> 1) & 3)) * 8;

  f32x4 acc[8][4] = {};
  short8 af[4], bf[4];

  // prologue: tile0 all 4 regions + tile1 kh0 pair; wait so tile0 landed (last 4 loads may fly)
  stageA(0, 0); stageB(0, 0); stageA(0, 1); stageB(0, 1); stageA(1, 0); stageB(1, 0);
  asm volatile("s_waitcnt vmcnt(4)" ::: "memory");
  __builtin_amdgcn_sched_barrier(0);
  __builtin_amdgcn_s_barrier();

#define PHASE(BC, KH, QM, STAGES) do{                                                   \
    if ((QM) == 0){                                                                     \
      _Pragma("unroll")                                                                 \
      for (int n = 0; n < 4; n++)                                                       \
        bf[n] = *(const short8*)&Bl[BC][KH][(wc * 64 + n * 16) * 32 + rdo];             \
    }                                                                                   \
    _Pragma("unroll")                                                                   \
    for (int m = 0; m < 4; m++)                                                         \
      af[m] = *(const short8*)&Al[BC][KH][(wr * 128 + (QM) * 64 + m * 16) * 32 + rdo];  \
    STAGES;                                                                             \
    __builtin_amdgcn_s_barrier();                                                       \
    asm volatile("s_waitcnt lgkmcnt(0)" ::: "memory");                                  \
    __builtin_amdgcn_sched_barrier(0);                                                  \
    __builtin_amdgcn_s_setprio(1);                                                      \
    _Pragma("unroll")                                                                   \
    for (int m = 0; m < 4; m++)                                                         \
      _Pragma("unroll")                                                                 \
      for (int n = 0; n < 4; n++)                                                       \
        acc[(QM) * 4 + m][n] = mfma16(af[m], bf[n], acc[(QM) * 4 + m][n]);              \
    __builtin_amdgcn_s_setprio(0);                                                      \
    __builtin_amdgcn_s_barrier();                                                       \
  }while(0)

  for (int t = 0; t < NT; t++){
    const int bc = t & 1;
    PHASE(bc, 0, 0, stageA(t + 1, 1));
    PHASE(bc, 0, 1, stageB(t + 1, 1));
    PHASE(bc, 1, 0, stageA(t + 2, 0));
    PHASE(bc, 1, 1, stageB(t + 2, 0));
    asm volatile("s_waitcnt vmcnt(4)" ::: "memory");
    __builtin_amdgcn_sched_barrier(0);
    __builtin_amdgcn_s_barrier();
  }
#undef PHASE

#pragma unroll
  for (int mq = 0; mq < 8; mq++){
#pragma unroll
    for (int n = 0; n < 4; n++){
      int c = col0 + wc * 64 + n * 16 + l16;
      float bb = bias[c];
#pragma unroll
      for (int i = 0; i < 4; i++){
        int r = row0 + wr * 128 + mq * 16 + lhi * 4 + i;
        float v = acc[mq][n][i] + bb;
        if constexpr (EPI == 1) v += R[(size_t)r * ldr + c];
        if constexpr (EPI == 2) v = gelu_f(v);
        if constexpr (OUT_BF16) ((u16*)Cv)[(size_t)r * ldc + c] = f2bf(v);
        else                    ((float*)Cv)[(size_t)r * ldc + c] = v;
      }
    }
  }
}

// ---------------- windowed attention + LePE, one wave per (window, head) ----------------
__global__ __launch_bounds__(64) void attn_kernel(
    const u16* __restrict__ qkv, const float* __restrict__ lw,
    const float* __restrict__ lb, u16* __restrict__ out)
{
  __shared__ float Ks[64][33];
  __shared__ float Vs[64][33];
  __shared__ float Wle[32][9];
  __shared__ float Lb[32];
  int head = blockIdx.x & 7, win = blockIdx.x >> 3;
  int wx = win & 7, wy = (win >> 3) & 7, b = win >> 6;
  int l  = threadIdx.x;           // query pixel in window
  int py = l >> 3, px = l & 7;
  size_t t = (size_t)b * 4096 + (size_t)(wy * 8 + py) * 64 + (wx * 8 + px);
  const u16* base = qkv + t * 768 + head * HD;

  float q[32];
#pragma unroll
  for (int j = 0; j < 32; j += 8){
    short8 vq = *(const short8*)(base + j);
    short8 vk = *(const short8*)(base + 256 + j);
    short8 vv = *(const short8*)(base + 512 + j);
#pragma unroll
    for (int e = 0; e < 8; e++){
      q[j + e]     = bf2f((u16)vq[e]) * SCALE_Q;
      Ks[l][j + e] = bf2f((u16)vk[e]);
      Vs[l][j + e] = bf2f((u16)vv[e]);
    }
  }
  for (int i = l; i < 288; i += 64) Wle[i / 9][i % 9] = lw[(head * 32 + i / 9) * 9 + (i % 9)];
  if (l < 32) Lb[l] = lb[head * 32 + l];
  __syncthreads();

  float sc[64];
  float mx = -1e30f;
#pragma unroll
  for (int k = 0; k < 64; k++){
    float s = 0.f;
#pragma unroll
    for (int d = 0; d < 32; d++) s += q[d] * Ks[k][d];
    sc[k] = s; mx = fmaxf(mx, s);
  }
  float sum = 0.f;
#pragma unroll
  for (int k = 0; k < 64; k++){ float e = __expf(sc[k] - mx); sc[k] = e; sum += e; }
  float inv = 1.0f / sum;
  float o[32];
#pragma unroll
  for (int d = 0; d < 32; d++) o[d] = 0.f;
#pragma unroll
  for (int k = 0; k < 64; k++){
    float p = sc[k] * inv;
#pragma unroll
    for (int d = 0; d < 32; d++) o[d] += p * Vs[k][d];
  }
  // LePE: depthwise 3x3 over the 8x8 window (zero pad at window edges)
#pragma unroll
  for (int ky = 0; ky < 3; ky++){
    int yy = py + ky - 1;
    if (yy < 0 || yy >= 8) continue;
#pragma unroll
    for (int kx = 0; kx < 3; kx++){
      int xx = px + kx - 1;
      if (xx < 0 || xx >= 8) continue;
      int kp = yy * 8 + xx;
#pragma unroll
      for (int d = 0; d < 32; d++) o[d] += Wle[d][ky * 3 + kx] * Vs[kp][d];
    }
  }
  u16* op = out + t * DIM + head * HD;
#pragma unroll
  for (int d = 0; d < 32; d++) op[d] = f2bf(o[d] + Lb[d]);
}

// ---------------- full-image depthwise 3x3 on img[..., 256:], thread = channel ----------------
__global__ __launch_bounds__(256) void convloc_kernel(const u16* __restrict__ img,
    const float* __restrict__ w, u16* __restrict__ out){
  int c  = threadIdx.x;
  int pg = blockIdx.x;            // 2048 groups of 16 pixels
  int b  = pg >> 8;
  int p0 = (pg & 255) * 16;
  float wt[9];
#pragma unroll
  for (int i = 0; i < 9; i++) wt[i] = w[c * 9 + i];
  for (int pi = 0; pi < 16; pi++){
    int p = p0 + pi;
    int y = p >> 6, x = p & 63;
    float acc = 0.f;
#pragma unroll
    for (int ky = 0; ky < 3; ky++){
      int yy = y + ky - 1;
      if (yy < 0 || yy >= 64) continue;
#pragma unroll
      for (int kx = 0; kx < 3; kx++){
        int xx = x + kx - 1;
        if (xx < 0 || xx >= 64) continue;
        acc += wt[ky * 3 + kx] * bf2f(img[((size_t)b * 4096 + yy * 64 + xx) * DIM + C2 + c]);
      }
    }
    out[((size_t)b * 4096 + p) * DIM + C2 + c] = f2bf(acc);
  }
}

extern "C" void kernel_launch(void* const* d_in, const int* in_sizes, int n_in,
                              void* d_out, int out_size, void* d_ws, size_t ws_size,
                              hipStream_t stream){
  const float* x      = (const float*)d_in[0];
  const float* n1g    = (const float*)d_in[1];
  const float* n1b    = (const float*)d_in[2];
  const float* qkv_w  = (const float*)d_in[3];
  const float* qkv_b  = (const float*)d_in[4];
  const float* lepe_w = (const float*)d_in[5];
  const float* lepe_b = (const float*)d_in[6];
  const float* conv_w = (const float*)d_in[7];
  const float* proj_w = (const float*)d_in[8];
  const float* proj_b = (const float*)d_in[9];
  const float* n2g    = (const float*)d_in[10];
  const float* n2b    = (const float*)d_in[11];
  const float* fc1_w  = (const float*)d_in[12];
  const float* fc1_b  = (const float*)d_in[13];
  const float* fc2_w  = (const float*)d_in[14];
  const float* fc2_b  = (const float*)d_in[15];
  float* out = (float*)d_out;

  char* ws = (char*)d_ws;
  u16* img     = (u16*)(ws + 0);
  u16* qkvb    = (u16*)(ws + 33554432ull);
  u16* localb  = (u16*)(ws + 83886080ull);
  u16* y       = (u16*)(ws + 0);
  u16* h       = (u16*)(ws + 33554432ull);
  u16* qkv_wT  = (u16*)(ws + 167772160ull);
  u16* proj_wT = (u16*)(ws + 167772160ull + 393216ull);
  u16* fc1_wT  = (u16*)(ws + 167772160ull + 393216ull + 524288ull);
  u16* fc2_wT  = (u16*)(ws + 167772160ull + 393216ull + 524288ull + 2097152ull);
  float* xa    = (float*)d_out;

  transpose_kernel<<<768, 256, 0, stream>>>(qkv_w, qkv_wT, 256, 768);
  transpose_kernel<<<1024, 256, 0, stream>>>(proj_w, proj_wT, 512, 512);
  transpose_kernel<<<4096, 256, 0, stream>>>(fc1_w, fc1_wT, 512, 2048);
  transpose_kernel<<<4096, 256, 0, stream>>>(fc2_w, fc2_wT, 2048, 512);

  ln_kernel<<<8192, 256, 0, stream>>>(x, n1g, n1b, img);

  dim3 gq(3, 128);   // x = col-blocks (256 wide), y = row-blocks
  gemm8_kernel<0, true><<<gq, 512, 0, stream>>>(img, DIM, qkv_wT, qkv_b, nullptr, 0, qkvb, 768, 256);

  attn_kernel<<<4096, 64, 0, stream>>>(qkvb, lepe_w, lepe_b, localb);
  convloc_kernel<<<2048, 256, 0, stream>>>(img, conv_w, localb);

  dim3 gp(2, 128);
  gemm8_kernel<1, false><<<gp, 512, 0, stream>>>(localb, DIM, proj_wT, proj_b, x, DIM, xa, DIM, 512);

  ln_kernel<<<8192, 256, 0, stream>>>(xa, n2g, n2b, y);

  dim3 g1(8, 128);
  gemm8_kernel<2, true><<<g1, 512, 0, stream>>>(y, DIM, fc1_wT, fc1_b, nullptr, 0, h, 2048, 512);

  dim3 g2(2, 128);
  gemm8_kernel<1, false><<<g2, 512, 0, stream>>>(h, 2048, fc2_wT, fc2_b, xa, DIM, out, DIM, 2048);
}

// Round 6
// 452.765 us; speedup vs baseline: 1.3211x; 1.1948x over previous
//
#include <hip/hip_runtime.h>
#include <cstdint>
#include <cstddef>

typedef unsigned short u16;
typedef __attribute__((ext_vector_type(8))) short short8;
typedef __attribute__((ext_vector_type(4))) float f32x4;

#define DIM 512
#define C2  256
#define HD  32
#define SCALE_Q 0.17677669529663689f

__device__ __forceinline__ float bf2f(u16 u){ return __uint_as_float(((unsigned)u) << 16); }
__device__ __forceinline__ u16 f2bf(float f){
  unsigned u = __float_as_uint(f);
  unsigned r = (u + 0x7FFFu + ((u >> 16) & 1u)) >> 16;
  return (u16)r;
}

__device__ __forceinline__ f32x4 mfma16(short8 a, short8 b, f32x4 c){
  return __builtin_amdgcn_mfma_f32_16x16x32_bf16(a, b, c, 0, 0, 0);
}

// async global->LDS, 16 bytes per lane; LDS dest is wave-uniform base (+lane*16 implied)
__device__ __forceinline__ void gload16(const u16* g, u16* l){
  __builtin_amdgcn_global_load_lds((const __attribute__((address_space(1))) void*)g,
                                   (__attribute__((address_space(3))) void*)l, 16, 0, 0);
}

// fast gelu (tanh form, hardware exp + rcp); |err| vs exact erf-gelu < 3e-3 absolute
__device__ __forceinline__ float gelu_f(float v){
  float z = 0.7978845608028654f * (v + 0.044715f * v * v * v);
  z = fminf(10.0f, fmaxf(-10.0f, z));
  float e = __expf(2.0f * z);
  float th = 1.0f - 2.0f * __builtin_amdgcn_rcpf(e + 1.0f);
  return 0.5f * v * (1.0f + th);
}

// ---------------- coalesced weight transpose + fp32->bf16 via LDS tile ----------------
// WT[n][k] = bf16(W[k][n]); grid (N/32, K/32), block 256
__global__ __launch_bounds__(256) void transpose_kernel(const float* __restrict__ W,
                                                        u16* __restrict__ WT, int K, int N){
  __shared__ u16 Tl[32][33];
  int n0 = blockIdx.x * 32, k0 = blockIdx.y * 32;
  int tx = threadIdx.x & 31, ty = threadIdx.x >> 5;   // ty 0..7
#pragma unroll
  for (int i = 0; i < 4; i++){
    int k = ty * 4 + i;
    Tl[k][tx] = f2bf(W[(size_t)(k0 + k) * N + n0 + tx]);
  }
  __syncthreads();
#pragma unroll
  for (int i = 0; i < 4; i++){
    int n = ty * 4 + i;
    WT[(size_t)(n0 + n) * K + k0 + tx] = Tl[tx][n];
  }
}

// ---------------- LayerNorm over last dim (512), one wave per row; fp32 in -> bf16 out ----------------
__global__ __launch_bounds__(256) void ln_kernel(const float* __restrict__ x, const float* __restrict__ g,
                                                 const float* __restrict__ bta, u16* __restrict__ out){
  int row  = blockIdx.x * 4 + (threadIdx.x >> 6);
  int lane = threadIdx.x & 63;
  size_t base = (size_t)row * DIM + lane * 8;
  float4 v0 = *(const float4*)(x + base);
  float4 v1 = *(const float4*)(x + base + 4);
  float f[8] = {v0.x, v0.y, v0.z, v0.w, v1.x, v1.y, v1.z, v1.w};
  float s = 0.f;
#pragma unroll
  for (int j = 0; j < 8; j++) s += f[j];
#pragma unroll
  for (int m = 1; m < 64; m <<= 1) s += __shfl_xor(s, m, 64);
  float mean = s * (1.0f / DIM);
  float vs = 0.f;
#pragma unroll
  for (int j = 0; j < 8; j++){ float d = f[j] - mean; vs += d * d; }
#pragma unroll
  for (int m = 1; m < 64; m <<= 1) vs += __shfl_xor(vs, m, 64);
  float rstd = rsqrtf(vs * (1.0f / DIM) + 1e-5f);
  float4 g0 = *(const float4*)(g + lane * 8);
  float4 g1 = *(const float4*)(g + lane * 8 + 4);
  float4 b0 = *(const float4*)(bta + lane * 8);
  float4 b1 = *(const float4*)(bta + lane * 8 + 4);
  float gg[8] = {g0.x, g0.y, g0.z, g0.w, g1.x, g1.y, g1.z, g1.w};
  float bb[8] = {b0.x, b0.y, b0.z, b0.w, b1.x, b1.y, b1.z, b1.w};
  short8 o;
#pragma unroll
  for (int j = 0; j < 8; j++){
    float r = (f[j] - mean) * rstd * gg[j] + bb[j];
    o[j] = (short)f2bf(r);
  }
  *(short8*)(out + base) = o;
}

// ---------------- GEMM, 256x256 8-phase schedule + vectorized LDS-bounce epilogue ----------------
// C[M x N] = A[M x K] @ W[K x N] (+bias, +epilogue)
// A bf16 row-major (lda); WT = bf16 W-transposed [N x K] row-major. K multiple of 128 (NT>=4).
// 8 waves (2M x 4N), per-wave C = 128x64. BK=64 split into two K-halves (kh) of 32.
// LDS: [2 dbuf][2 kh][256 rows][32 cols] per matrix = 64 KB each, 128 KB total.
// Staging: global_load_lds w16, linear LDS dest + inverse-swizzled global source;
// reads use slot = lhi ^ ((row>>1)&3)  (bank-conflict-free, both-sides rule).
// Drain: vmcnt(4) steady state, vmcnt(0) for the last two tiles (t+2 stages skipped there).
// Epilogue: per-wave LDS transpose patch -> float4/ushort4 vectorized R-load + C-store.
template<int EPI, bool OUT_BF16>
__global__ __launch_bounds__(512, 2) void gemm8_kernel(
    const u16* __restrict__ A, int lda,
    const u16* __restrict__ WT,
    const float* __restrict__ bias,
    const float* R, int ldr,
    void* Cv, int ldc, int K)
{
  __shared__ u16 Al[2][2][256 * 32];
  __shared__ u16 Bl[2][2][256 * 32];
  const int tid = threadIdx.x;
  const int l   = tid & 63;
  const int w   = tid >> 6;        // wave 0..7
  const int wr  = w >> 2;          // M half
  const int wc  = w & 3;           // N quarter
  const int l16 = l & 15, lhi = l >> 4;

  // XCD-chunked swizzle (nwg % 8 == 0 for all our grids): consecutive tiles -> same XCD L2
  const int gx = gridDim.x;
  int bid = blockIdx.y * gx + blockIdx.x;
  int nwg = gx * gridDim.y;
  int sw  = (nwg & 7) ? bid : ((bid & 7) * (nwg >> 3) + (bid >> 3));
  const int col0 = (sw % gx) * 256, row0 = (sw / gx) * 256;
  const int NT = K >> 6;

  // per-lane staging source: lane covers LDS row (w*16 + l/4), slot (l&3).
  // source col-group = slot ^ ((row>>1)&3) = (l&3) ^ ((l>>3)&3)
  const int srow = w * 16 + (l >> 2);
  const int cs   = (((l & 3) ^ ((l >> 3) & 3)) * 8);
  const u16* pA = A  + (size_t)(row0 + srow) * lda + cs;
  const u16* pB = WT + (size_t)(col0 + srow) * K  + cs;
  const size_t a128 = (size_t)128 * lda, b128 = (size_t)128 * K;

  auto stageA = [&](int tt, int hh){
    if (tt < NT){
      size_t go = (size_t)tt * 64 + (size_t)hh * 32;
      gload16(pA + go,        &Al[tt & 1][hh][(w * 16) * 32]);
      gload16(pA + a128 + go, &Al[tt & 1][hh][(128 + w * 16) * 32]);
    }
  };
  auto stageB = [&](int tt, int hh){
    if (tt < NT){
      size_t go = (size_t)tt * 64 + (size_t)hh * 32;
      gload16(pB + go,        &Bl[tt & 1][hh][(w * 16) * 32]);
      gload16(pB + b128 + go, &Bl[tt & 1][hh][(128 + w * 16) * 32]);
    }
  };

  // per-lane read offset within a [256][32] region (u16 units), slot-swizzled
  const int rdo = l16 * 32 + (lhi ^ ((l16 >> 1) & 3)) * 8;

  f32x4 acc[8][4] = {};
  short8 af[4], bf[4];

  // prologue: tile0 all 4 regions + tile1 kh0 pair; vmcnt(4) -> tile0 landed
  stageA(0, 0); stageB(0, 0); stageA(0, 1); stageB(0, 1); stageA(1, 0); stageB(1, 0);
  asm volatile("s_waitcnt vmcnt(4)" ::: "memory");
  __builtin_amdgcn_sched_barrier(0);
  __builtin_amdgcn_s_barrier();

#define PHASE(BC, KH, QM, STAGES) do{                                                   \
    if ((QM) == 0){                                                                     \
      _Pragma("unroll")                                                                 \
      for (int n = 0; n < 4; n++)                                                       \
        bf[n] = *(const short8*)&Bl[BC][KH][(wc * 64 + n * 16) * 32 + rdo];             \
    }                                                                                   \
    _Pragma("unroll")                                                                   \
    for (int m = 0; m < 4; m++)                                                         \
      af[m] = *(const short8*)&Al[BC][KH][(wr * 128 + (QM) * 64 + m * 16) * 32 + rdo];  \
    STAGES;                                                                             \
    __builtin_amdgcn_s_barrier();                                                       \
    asm volatile("s_waitcnt lgkmcnt(0)" ::: "memory");                                  \
    __builtin_amdgcn_sched_barrier(0);                                                  \
    __builtin_amdgcn_s_setprio(1);                                                      \
    _Pragma("unroll")                                                                   \
    for (int m = 0; m < 4; m++)                                                         \
      _Pragma("unroll")                                                                 \
      for (int n = 0; n < 4; n++)                                                       \
        acc[(QM) * 4 + m][n] = mfma16(af[m], bf[n], acc[(QM) * 4 + m][n]);              \
    __builtin_amdgcn_s_setprio(0);                                                      \
    __builtin_amdgcn_s_barrier();                                                       \
  }while(0)

  for (int t = 0; t < NT; t++){
    const int bc = t & 1;
    PHASE(bc, 0, 0, stageA(t + 1, 1));
    PHASE(bc, 0, 1, stageB(t + 1, 1));
    PHASE(bc, 1, 0, stageA(t + 2, 0));
    PHASE(bc, 1, 1, stageB(t + 2, 0));
    if (t + 2 < NT) asm volatile("s_waitcnt vmcnt(4)" ::: "memory");
    else            asm volatile("s_waitcnt vmcnt(0)" ::: "memory");
    __builtin_amdgcn_sched_barrier(0);
    __builtin_amdgcn_s_barrier();
  }
#undef PHASE

  // ---- vectorized epilogue: per-wave LDS transpose patch (reuses Al; no barriers needed) ----
  float* Tf = (float*)&Al[0][0][0] + w * (16 * 68);   // 16 rows x 68 cols fp32 per wave
  const int gcol = col0 + wc * 64 + (l & 15) * 4;     // this lane's 4 output cols (gather phase)
  const float4 bv = *(const float4*)&bias[gcol];
#pragma unroll
  for (int mq = 0; mq < 8; mq++){
#pragma unroll
    for (int n = 0; n < 4; n++)
#pragma unroll
      for (int i = 0; i < 4; i++)
        Tf[(lhi * 4 + i) * 68 + n * 16 + l16] = acc[mq][n][i];
    // same-wave DS ordering + compiler lgkmcnt protect the read-back
#pragma unroll
    for (int p = 0; p < 4; p++){
      int lr = p * 4 + (l >> 4);                       // local row 0..15
      f32x4 v = *(const f32x4*)&Tf[lr * 68 + (l & 15) * 4];
      int grow = row0 + wr * 128 + mq * 16 + lr;
      float4 vv = { v[0] + bv.x, v[1] + bv.y, v[2] + bv.z, v[3] + bv.w };
      if constexpr (EPI == 1){
        float4 rv = *(const float4*)&R[(size_t)grow * ldr + gcol];
        vv.x += rv.x; vv.y += rv.y; vv.z += rv.z; vv.w += rv.w;
      }
      if constexpr (EPI == 2){
        vv.x = gelu_f(vv.x); vv.y = gelu_f(vv.y); vv.z = gelu_f(vv.z); vv.w = gelu_f(vv.w);
      }
      if constexpr (OUT_BF16){
        ushort4 o4 = { f2bf(vv.x), f2bf(vv.y), f2bf(vv.z), f2bf(vv.w) };
        *(ushort4*)&((u16*)Cv)[(size_t)grow * ldc + gcol] = o4;
      } else {
        *(float4*)&((float*)Cv)[(size_t)grow * ldc + gcol] = vv;
      }
    }
  }
}

// ---------------- windowed attention + LePE, one wave per (window, head) ----------------
__global__ __launch_bounds__(64) void attn_kernel(
    const u16* __restrict__ qkv, const float* __restrict__ lw,
    const float* __restrict__ lb, u16* __restrict__ out)
{
  __shared__ float Ks[64][33];
  __shared__ float Vs[64][33];
  __shared__ float Wle[32][9];
  __shared__ float Lb[32];
  int head = blockIdx.x & 7, win = blockIdx.x >> 3;
  int wx = win & 7, wy = (win >> 3) & 7, b = win >> 6;
  int l  = threadIdx.x;           // query pixel in window
  int py = l >> 3, px = l & 7;
  size_t t = (size_t)b * 4096 + (size_t)(wy * 8 + py) * 64 + (wx * 8 + px);
  const u16* base = qkv + t * 768 + head * HD;

  float q[32];
#pragma unroll
  for (int j = 0; j < 32; j += 8){
    short8 vq = *(const short8*)(base + j);
    short8 vk = *(const short8*)(base + 256 + j);
    short8 vv = *(const short8*)(base + 512 + j);
#pragma unroll
    for (int e = 0; e < 8; e++){
      q[j + e]     = bf2f((u16)vq[e]) * SCALE_Q;
      Ks[l][j + e] = bf2f((u16)vk[e]);
      Vs[l][j + e] = bf2f((u16)vv[e]);
    }
  }
  for (int i = l; i < 288; i += 64) Wle[i / 9][i % 9] = lw[(head * 32 + i / 9) * 9 + (i % 9)];
  if (l < 32) Lb[l] = lb[head * 32 + l];
  __syncthreads();

  float sc[64];
  float mx = -1e30f;
#pragma unroll
  for (int k = 0; k < 64; k++){
    float s = 0.f;
#pragma unroll
    for (int d = 0; d < 32; d++) s += q[d] * Ks[k][d];
    sc[k] = s; mx = fmaxf(mx, s);
  }
  float sum = 0.f;
#pragma unroll
  for (int k = 0; k < 64; k++){ float e = __expf(sc[k] - mx); sc[k] = e; sum += e; }
  float inv = 1.0f / sum;
  float o[32];
#pragma unroll
  for (int d = 0; d < 32; d++) o[d] = 0.f;
#pragma unroll
  for (int k = 0; k < 64; k++){
    float p = sc[k] * inv;
#pragma unroll
    for (int d = 0; d < 32; d++) o[d] += p * Vs[k][d];
  }
  // LePE: depthwise 3x3 over the 8x8 window (zero pad at window edges)
#pragma unroll
  for (int ky = 0; ky < 3; ky++){
    int yy = py + ky - 1;
    if (yy < 0 || yy >= 8) continue;
#pragma unroll
    for (int kx = 0; kx < 3; kx++){
      int xx = px + kx - 1;
      if (xx < 0 || xx >= 8) continue;
      int kp = yy * 8 + xx;
#pragma unroll
      for (int d = 0; d < 32; d++) o[d] += Wle[d][ky * 3 + kx] * Vs[kp][d];
    }
  }
  u16* op = out + t * DIM + head * HD;
#pragma unroll
  for (int d = 0; d < 32; d += 4){
    ushort4 o4 = { f2bf(o[d] + Lb[d]), f2bf(o[d + 1] + Lb[d + 1]),
                   f2bf(o[d + 2] + Lb[d + 2]), f2bf(o[d + 3] + Lb[d + 3]) };
    *(ushort4*)&op[d] = o4;
  }
}

// ---------------- full-image depthwise 3x3 on img[..., 256:], thread = channel ----------------
__global__ __launch_bounds__(256) void convloc_kernel(const u16* __restrict__ img,
    const float* __restrict__ w, u16* __restrict__ out){
  int c  = threadIdx.x;
  int pg = blockIdx.x;            // 2048 groups of 16 pixels
  int b  = pg >> 8;
  int p0 = (pg & 255) * 16;
  float wt[9];
#pragma unroll
  for (int i = 0; i < 9; i++) wt[i] = w[c * 9 + i];
  for (int pi = 0; pi < 16; pi++){
    int p = p0 + pi;
    int y = p >> 6, x = p & 63;
    float acc = 0.f;
#pragma unroll
    for (int ky = 0; ky < 3; ky++){
      int yy = y + ky - 1;
      if (yy < 0 || yy >= 64) continue;
#pragma unroll
      for (int kx = 0; kx < 3; kx++){
        int xx = x + kx - 1;
        if (xx < 0 || xx >= 64) continue;
        acc += wt[ky * 3 + kx] * bf2f(img[((size_t)b * 4096 + yy * 64 + xx) * DIM + C2 + c]);
      }
    }
    out[((size_t)b * 4096 + p) * DIM + C2 + c] = f2bf(acc);
  }
}

extern "C" void kernel_launch(void* const* d_in, const int* in_sizes, int n_in,
                              void* d_out, int out_size, void* d_ws, size_t ws_size,
                              hipStream_t stream){
  const float* x      = (const float*)d_in[0];
  const float* n1g    = (const float*)d_in[1];
  const float* n1b    = (const float*)d_in[2];
  const float* qkv_w  = (const float*)d_in[3];
  const float* qkv_b  = (const float*)d_in[4];
  const float* lepe_w = (const float*)d_in[5];
  const float* lepe_b = (const float*)d_in[6];
  const float* conv_w = (const float*)d_in[7];
  const float* proj_w = (const float*)d_in[8];
  const float* proj_b = (const float*)d_in[9];
  const float* n2g    = (const float*)d_in[10];
  const float* n2b    = (const float*)d_in[11];
  const float* fc1_w  = (const float*)d_in[12];
  const float* fc1_b  = (const float*)d_in[13];
  const float* fc2_w  = (const float*)d_in[14];
  const float* fc2_b  = (const float*)d_in[15];
  float* out = (float*)d_out;

  char* ws = (char*)d_ws;
  u16* img     = (u16*)(ws + 0);
  u16* qkvb    = (u16*)(ws + 33554432ull);
  u16* localb  = (u16*)(ws + 83886080ull);
  u16* y       = (u16*)(ws + 0);
  u16* h       = (u16*)(ws + 33554432ull);
  u16* qkv_wT  = (u16*)(ws + 167772160ull);
  u16* proj_wT = (u16*)(ws + 167772160ull + 393216ull);
  u16* fc1_wT  = (u16*)(ws + 167772160ull + 393216ull + 524288ull);
  u16* fc2_wT  = (u16*)(ws + 167772160ull + 393216ull + 524288ull + 2097152ull);
  float* xa    = (float*)d_out;

  { dim3 g(24, 8);  transpose_kernel<<<g, 256, 0, stream>>>(qkv_w,  qkv_wT,  256, 768);  }
  { dim3 g(16, 16); transpose_kernel<<<g, 256, 0, stream>>>(proj_w, proj_wT, 512, 512);  }
  { dim3 g(64, 16); transpose_kernel<<<g, 256, 0, stream>>>(fc1_w,  fc1_wT,  512, 2048); }
  { dim3 g(16, 64); transpose_kernel<<<g, 256, 0, stream>>>(fc2_w,  fc2_wT,  2048, 512); }

  ln_kernel<<<8192, 256, 0, stream>>>(x, n1g, n1b, img);

  dim3 gq(3, 128);   // x = col-blocks (256 wide), y = row-blocks
  gemm8_kernel<0, true><<<gq, 512, 0, stream>>>(img, DIM, qkv_wT, qkv_b, nullptr, 0, qkvb, 768, 256);

  attn_kernel<<<4096, 64, 0, stream>>>(qkvb, lepe_w, lepe_b, localb);
  convloc_kernel<<<2048, 256, 0, stream>>>(img, conv_w, localb);

  dim3 gp(2, 128);
  gemm8_kernel<1, false><<<gp, 512, 0, stream>>>(localb, DIM, proj_wT, proj_b, x, DIM, xa, DIM, 512);

  ln_kernel<<<8192, 256, 0, stream>>>(xa, n2g, n2b, y);

  dim3 g1(8, 128);
  gemm8_kernel<2, true><<<g1, 512, 0, stream>>>(y, DIM, fc1_wT, fc1_b, nullptr, 0, h, 2048, 512);

  dim3 g2(2, 128);
  gemm8_kernel<1, false><<<g2, 512, 0, stream>>>(h, 2048, fc2_wT, fc2_b, xa, DIM, out, DIM, 2048);
}

// Round 7
// 449.306 us; speedup vs baseline: 1.3313x; 1.0077x over previous
//
#include <hip/hip_runtime.h>
#include <cstdint>
#include <cstddef>

typedef unsigned short u16;
typedef __attribute__((ext_vector_type(8))) short short8;
typedef __attribute__((ext_vector_type(4))) float f32x4;

#define DIM 512
#define C2  256
#define HD  32
#define SCALE_Q 0.17677669529663689f

__device__ __forceinline__ float bf2f(u16 u){ return __uint_as_float(((unsigned)u) << 16); }
__device__ __forceinline__ u16 f2bf(float f){
  unsigned u = __float_as_uint(f);
  unsigned r = (u + 0x7FFFu + ((u >> 16) & 1u)) >> 16;
  return (u16)r;
}

__device__ __forceinline__ f32x4 mfma16(short8 a, short8 b, f32x4 c){
  return __builtin_amdgcn_mfma_f32_16x16x32_bf16(a, b, c, 0, 0, 0);
}

// async global->LDS, 16 bytes per lane; LDS dest is wave-uniform base (+lane*16 implied)
__device__ __forceinline__ void gload16(const u16* g, u16* l){
  __builtin_amdgcn_global_load_lds((const __attribute__((address_space(1))) void*)g,
                                   (__attribute__((address_space(3))) void*)l, 16, 0, 0);
}

// fast gelu: v * sigmoid(1.702 v)  (6 VALU ops; |err| vs exact erf-gelu <= ~0.02 abs)
__device__ __forceinline__ float gelu_f(float v){
  float e = __expf(-1.702f * v);
  return v * __builtin_amdgcn_rcpf(1.0f + e);
}

// ---------------- coalesced weight transpose + fp32->bf16 via LDS tile ----------------
// WT[n][k] = bf16(W[k][n]); grid (N/32, K/32), block 256
__global__ __launch_bounds__(256) void transpose_kernel(const float* __restrict__ W,
                                                        u16* __restrict__ WT, int K, int N){
  __shared__ u16 Tl[32][33];
  int n0 = blockIdx.x * 32, k0 = blockIdx.y * 32;
  int tx = threadIdx.x & 31, ty = threadIdx.x >> 5;   // ty 0..7
#pragma unroll
  for (int i = 0; i < 4; i++){
    int k = ty * 4 + i;
    Tl[k][tx] = f2bf(W[(size_t)(k0 + k) * N + n0 + tx]);
  }
  __syncthreads();
#pragma unroll
  for (int i = 0; i < 4; i++){
    int n = ty * 4 + i;
    WT[(size_t)(n0 + n) * K + k0 + tx] = Tl[tx][n];
  }
}

// ---------------- LayerNorm over last dim (512), one wave per row; fp32 in -> bf16 out ----------------
__global__ __launch_bounds__(256) void ln_kernel(const float* __restrict__ x, const float* __restrict__ g,
                                                 const float* __restrict__ bta, u16* __restrict__ out){
  int row  = blockIdx.x * 4 + (threadIdx.x >> 6);
  int lane = threadIdx.x & 63;
  size_t base = (size_t)row * DIM + lane * 8;
  float4 v0 = *(const float4*)(x + base);
  float4 v1 = *(const float4*)(x + base + 4);
  float f[8] = {v0.x, v0.y, v0.z, v0.w, v1.x, v1.y, v1.z, v1.w};
  float s = 0.f;
#pragma unroll
  for (int j = 0; j < 8; j++) s += f[j];
#pragma unroll
  for (int m = 1; m < 64; m <<= 1) s += __shfl_xor(s, m, 64);
  float mean = s * (1.0f / DIM);
  float vs = 0.f;
#pragma unroll
  for (int j = 0; j < 8; j++){ float d = f[j] - mean; vs += d * d; }
#pragma unroll
  for (int m = 1; m < 64; m <<= 1) vs += __shfl_xor(vs, m, 64);
  float rstd = rsqrtf(vs * (1.0f / DIM) + 1e-5f);
  float4 g0 = *(const float4*)(g + lane * 8);
  float4 g1 = *(const float4*)(g + lane * 8 + 4);
  float4 b0 = *(const float4*)(bta + lane * 8);
  float4 b1 = *(const float4*)(bta + lane * 8 + 4);
  float gg[8] = {g0.x, g0.y, g0.z, g0.w, g1.x, g1.y, g1.z, g1.w};
  float bb[8] = {b0.x, b0.y, b0.z, b0.w, b1.x, b1.y, b1.z, b1.w};
  short8 o;
#pragma unroll
  for (int j = 0; j < 8; j++){
    float r = (f[j] - mean) * rstd * gg[j] + bb[j];
    o[j] = (short)f2bf(r);
  }
  *(short8*)(out + base) = o;
}

// ---------------- GEMM, 256x256 8-phase schedule, swapped-operand (transposed) fragments ----------------
// C[M x N] = A[M x K] @ W[K x N] (+bias, +epilogue)
// A bf16 row-major (lda); WT = bf16 W-transposed [N x K] row-major. K multiple of 128 (NT>=4).
// 8 waves (2M x 4N), per-wave C = 128x64. BK=64 split into two K-halves (kh) of 32.
// LDS: [2 dbuf][2 kh][256 rows][32 cols] per matrix = 64 KB each, 128 KB total.
// Staging: global_load_lds w16, linear LDS dest + inverse-swizzled global source;
// reads use slot = lhi ^ ((row>>1)&3)  (bank-conflict-free, both-sides rule).
// MFMA operands SWAPPED: acc = mfma(bf, af) -> lane holds C[row = l16][col = lhi*4+i]
// => epilogue is direct float4/ushort4 stores, no LDS transpose needed.
// Drain: vmcnt(4) steady state, vmcnt(0) for the last two tiles (t+2 stages skipped there).
template<int EPI, bool OUT_BF16>
__global__ __launch_bounds__(512, 2) void gemm8_kernel(
    const u16* __restrict__ A, int lda,
    const u16* __restrict__ WT,
    const float* __restrict__ bias,
    const float* R, int ldr,
    void* Cv, int ldc, int K)
{
  __shared__ u16 Al[2][2][256 * 32];
  __shared__ u16 Bl[2][2][256 * 32];
  const int tid = threadIdx.x;
  const int l   = tid & 63;
  const int w   = tid >> 6;        // wave 0..7
  const int wr  = w >> 2;          // M half
  const int wc  = w & 3;           // N quarter
  const int l16 = l & 15, lhi = l >> 4;

  // XCD-chunked swizzle (nwg % 8 == 0 for all our grids): consecutive tiles -> same XCD L2
  const int gx = gridDim.x;
  int bid = blockIdx.y * gx + blockIdx.x;
  int nwg = gx * gridDim.y;
  int sw  = (nwg & 7) ? bid : ((bid & 7) * (nwg >> 3) + (bid >> 3));
  const int col0 = (sw % gx) * 256, row0 = (sw / gx) * 256;
  const int NT = K >> 6;

  // per-lane staging source: lane covers LDS row (w*16 + l/4), slot (l&3).
  // source col-group = slot ^ ((row>>1)&3) = (l&3) ^ ((l>>3)&3)
  const int srow = w * 16 + (l >> 2);
  const int cs   = (((l & 3) ^ ((l >> 3) & 3)) * 8);
  const u16* pA = A  + (size_t)(row0 + srow) * lda + cs;
  const u16* pB = WT + (size_t)(col0 + srow) * K  + cs;
  const size_t a128 = (size_t)128 * lda, b128 = (size_t)128 * K;

  auto stageA = [&](int tt, int hh){
    if (tt < NT){
      size_t go = (size_t)tt * 64 + (size_t)hh * 32;
      gload16(pA + go,        &Al[tt & 1][hh][(w * 16) * 32]);
      gload16(pA + a128 + go, &Al[tt & 1][hh][(128 + w * 16) * 32]);
    }
  };
  auto stageB = [&](int tt, int hh){
    if (tt < NT){
      size_t go = (size_t)tt * 64 + (size_t)hh * 32;
      gload16(pB + go,        &Bl[tt & 1][hh][(w * 16) * 32]);
      gload16(pB + b128 + go, &Bl[tt & 1][hh][(128 + w * 16) * 32]);
    }
  };

  // per-lane read offset within a [256][32] region (u16 units), slot-swizzled
  const int rdo = l16 * 32 + (lhi ^ ((l16 >> 1) & 3)) * 8;

  f32x4 acc[8][4] = {};
  short8 af[4], bf[4];

  // prologue: tile0 all 4 regions + tile1 kh0 pair; vmcnt(4) -> tile0 landed
  stageA(0, 0); stageB(0, 0); stageA(0, 1); stageB(0, 1); stageA(1, 0); stageB(1, 0);
  asm volatile("s_waitcnt vmcnt(4)" ::: "memory");
  __builtin_amdgcn_sched_barrier(0);
  __builtin_amdgcn_s_barrier();

#define PHASE(BC, KH, QM, STAGES) do{                                                   \
    if ((QM) == 0){                                                                     \
      _Pragma("unroll")                                                                 \
      for (int n = 0; n < 4; n++)                                                       \
        bf[n] = *(const short8*)&Bl[BC][KH][(wc * 64 + n * 16) * 32 + rdo];             \
    }                                                                                   \
    _Pragma("unroll")                                                                   \
    for (int m = 0; m < 4; m++)                                                         \
      af[m] = *(const short8*)&Al[BC][KH][(wr * 128 + (QM) * 64 + m * 16) * 32 + rdo];  \
    STAGES;                                                                             \
    __builtin_amdgcn_s_barrier();                                                       \
    asm volatile("s_waitcnt lgkmcnt(0)" ::: "memory");                                  \
    __builtin_amdgcn_sched_barrier(0);                                                  \
    __builtin_amdgcn_s_setprio(1);                                                      \
    _Pragma("unroll")                                                                   \
    for (int m = 0; m < 4; m++)                                                         \
      _Pragma("unroll")                                                                 \
      for (int n = 0; n < 4; n++)                                                       \
        acc[(QM) * 4 + m][n] = mfma16(bf[n], af[m], acc[(QM) * 4 + m][n]);              \
    __builtin_amdgcn_s_setprio(0);                                                      \
    __builtin_amdgcn_s_barrier();                                                       \
  }while(0)

  for (int t = 0; t < NT; t++){
    const int bc = t & 1;
    PHASE(bc, 0, 0, stageA(t + 1, 1));
    PHASE(bc, 0, 1, stageB(t + 1, 1));
    PHASE(bc, 1, 0, stageA(t + 2, 0));
    PHASE(bc, 1, 1, stageB(t + 2, 0));
    if (t + 2 < NT) asm volatile("s_waitcnt vmcnt(4)" ::: "memory");
    else            asm volatile("s_waitcnt vmcnt(0)" ::: "memory");
    __builtin_amdgcn_sched_barrier(0);
    __builtin_amdgcn_s_barrier();
  }
#undef PHASE

  // ---- direct vectorized epilogue (no LDS): lane owns row = l16, cols = lhi*4+{0..3} per fragment ----
  float4 bvs[4];
#pragma unroll
  for (int n = 0; n < 4; n++)
    bvs[n] = *(const float4*)&bias[col0 + wc * 64 + n * 16 + lhi * 4];
#pragma unroll
  for (int mq = 0; mq < 8; mq++){
    int grow = row0 + wr * 128 + mq * 16 + l16;
#pragma unroll
    for (int n = 0; n < 4; n++){
      int gcol = col0 + wc * 64 + n * 16 + lhi * 4;
      float4 vv = { acc[mq][n][0] + bvs[n].x, acc[mq][n][1] + bvs[n].y,
                    acc[mq][n][2] + bvs[n].z, acc[mq][n][3] + bvs[n].w };
      if constexpr (EPI == 1){
        float4 rv = *(const float4*)&R[(size_t)grow * ldr + gcol];
        vv.x += rv.x; vv.y += rv.y; vv.z += rv.z; vv.w += rv.w;
      }
      if constexpr (EPI == 2){
        vv.x = gelu_f(vv.x); vv.y = gelu_f(vv.y); vv.z = gelu_f(vv.z); vv.w = gelu_f(vv.w);
      }
      if constexpr (OUT_BF16){
        ushort4 o4 = { f2bf(vv.x), f2bf(vv.y), f2bf(vv.z), f2bf(vv.w) };
        *(ushort4*)&((u16*)Cv)[(size_t)grow * ldc + gcol] = o4;
      } else {
        *(float4*)&((float*)Cv)[(size_t)grow * ldc + gcol] = vv;
      }
    }
  }
}

// ---------------- windowed attention + LePE, one wave per (window, head) ----------------
__global__ __launch_bounds__(64) void attn_kernel(
    const u16* __restrict__ qkv, const float* __restrict__ lw,
    const float* __restrict__ lb, u16* __restrict__ out)
{
  __shared__ float Ks[64][33];
  __shared__ float Vs[64][33];
  __shared__ float Wle[32][9];
  __shared__ float Lb[32];
  int head = blockIdx.x & 7, win = blockIdx.x >> 3;
  int wx = win & 7, wy = (win >> 3) & 7, b = win >> 6;
  int l  = threadIdx.x;           // query pixel in window
  int py = l >> 3, px = l & 7;
  size_t t = (size_t)b * 4096 + (size_t)(wy * 8 + py) * 64 + (wx * 8 + px);
  const u16* base = qkv + t * 768 + head * HD;

  float q[32];
#pragma unroll
  for (int j = 0; j < 32; j += 8){
    short8 vq = *(const short8*)(base + j);
    short8 vk = *(const short8*)(base + 256 + j);
    short8 vv = *(const short8*)(base + 512 + j);
#pragma unroll
    for (int e = 0; e < 8; e++){
      q[j + e]     = bf2f((u16)vq[e]) * SCALE_Q;
      Ks[l][j + e] = bf2f((u16)vk[e]);
      Vs[l][j + e] = bf2f((u16)vv[e]);
    }
  }
  for (int i = l; i < 288; i += 64) Wle[i / 9][i % 9] = lw[(head * 32 + i / 9) * 9 + (i % 9)];
  if (l < 32) Lb[l] = lb[head * 32 + l];
  __syncthreads();

  float sc[64];
  float mx = -1e30f;
#pragma unroll
  for (int k = 0; k < 64; k++){
    float s = 0.f;
#pragma unroll
    for (int d = 0; d < 32; d++) s += q[d] * Ks[k][d];
    sc[k] = s; mx = fmaxf(mx, s);
  }
  float sum = 0.f;
#pragma unroll
  for (int k = 0; k < 64; k++){ float e = __expf(sc[k] - mx); sc[k] = e; sum += e; }
  float inv = 1.0f / sum;
  float o[32];
#pragma unroll
  for (int d = 0; d < 32; d++) o[d] = 0.f;
#pragma unroll
  for (int k = 0; k < 64; k++){
    float p = sc[k] * inv;
#pragma unroll
    for (int d = 0; d < 32; d++) o[d] += p * Vs[k][d];
  }
  // LePE: depthwise 3x3 over the 8x8 window (zero pad at window edges)
#pragma unroll
  for (int ky = 0; ky < 3; ky++){
    int yy = py + ky - 1;
    if (yy < 0 || yy >= 8) continue;
#pragma unroll
    for (int kx = 0; kx < 3; kx++){
      int xx = px + kx - 1;
      if (xx < 0 || xx >= 8) continue;
      int kp = yy * 8 + xx;
#pragma unroll
      for (int d = 0; d < 32; d++) o[d] += Wle[d][ky * 3 + kx] * Vs[kp][d];
    }
  }
  u16* op = out + t * DIM + head * HD;
#pragma unroll
  for (int d = 0; d < 32; d += 4){
    ushort4 o4 = { f2bf(o[d] + Lb[d]), f2bf(o[d + 1] + Lb[d + 1]),
                   f2bf(o[d + 2] + Lb[d + 2]), f2bf(o[d + 3] + Lb[d + 3]) };
    *(ushort4*)&op[d] = o4;
  }
}

// ---------------- full-image depthwise 3x3 on img[..., 256:], thread = channel ----------------
__global__ __launch_bounds__(256) void convloc_kernel(const u16* __restrict__ img,
    const float* __restrict__ w, u16* __restrict__ out){
  int c  = threadIdx.x;
  int pg = blockIdx.x;            // 2048 groups of 16 pixels
  int b  = pg >> 8;
  int p0 = (pg & 255) * 16;
  float wt[9];
#pragma unroll
  for (int i = 0; i < 9; i++) wt[i] = w[c * 9 + i];
  for (int pi = 0; pi < 16; pi++){
    int p = p0 + pi;
    int y = p >> 6, x = p & 63;
    float acc = 0.f;
#pragma unroll
    for (int ky = 0; ky < 3; ky++){
      int yy = y + ky - 1;
      if (yy < 0 || yy >= 64) continue;
#pragma unroll
      for (int kx = 0; kx < 3; kx++){
        int xx = x + kx - 1;
        if (xx < 0 || xx >= 64) continue;
        acc += wt[ky * 3 + kx] * bf2f(img[((size_t)b * 4096 + yy * 64 + xx) * DIM + C2 + c]);
      }
    }
    out[((size_t)b * 4096 + p) * DIM + C2 + c] = f2bf(acc);
  }
}

extern "C" void kernel_launch(void* const* d_in, const int* in_sizes, int n_in,
                              void* d_out, int out_size, void* d_ws, size_t ws_size,
                              hipStream_t stream){
  const float* x      = (const float*)d_in[0];
  const float* n1g    = (const float*)d_in[1];
  const float* n1b    = (const float*)d_in[2];
  const float* qkv_w  = (const float*)d_in[3];
  const float* qkv_b  = (const float*)d_in[4];
  const float* lepe_w = (const float*)d_in[5];
  const float* lepe_b = (const float*)d_in[6];
  const float* conv_w = (const float*)d_in[7];
  const float* proj_w = (const float*)d_in[8];
  const float* proj_b = (const float*)d_in[9];
  const float* n2g    = (const float*)d_in[10];
  const float* n2b    = (const float*)d_in[11];
  const float* fc1_w  = (const float*)d_in[12];
  const float* fc1_b  = (const float*)d_in[13];
  const float* fc2_w  = (const float*)d_in[14];
  const float* fc2_b  = (const float*)d_in[15];
  float* out = (float*)d_out;

  char* ws = (char*)d_ws;
  u16* img     = (u16*)(ws + 0);
  u16* qkvb    = (u16*)(ws + 33554432ull);
  u16* localb  = (u16*)(ws + 83886080ull);
  u16* y       = (u16*)(ws + 0);
  u16* h       = (u16*)(ws + 33554432ull);
  u16* qkv_wT  = (u16*)(ws + 167772160ull);
  u16* proj_wT = (u16*)(ws + 167772160ull + 393216ull);
  u16* fc1_wT  = (u16*)(ws + 167772160ull + 393216ull + 524288ull);
  u16* fc2_wT  = (u16*)(ws + 167772160ull + 393216ull + 524288ull + 2097152ull);
  float* xa    = (float*)d_out;

  { dim3 g(24, 8);  transpose_kernel<<<g, 256, 0, stream>>>(qkv_w,  qkv_wT,  256, 768);  }
  { dim3 g(16, 16); transpose_kernel<<<g, 256, 0, stream>>>(proj_w, proj_wT, 512, 512);  }
  { dim3 g(64, 16); transpose_kernel<<<g, 256, 0, stream>>>(fc1_w,  fc1_wT,  512, 2048); }
  { dim3 g(16, 64); transpose_kernel<<<g, 256, 0, stream>>>(fc2_w,  fc2_wT,  2048, 512); }

  ln_kernel<<<8192, 256, 0, stream>>>(x, n1g, n1b, img);

  dim3 gq(3, 128);   // x = col-blocks (256 wide), y = row-blocks
  gemm8_kernel<0, true><<<gq, 512, 0, stream>>>(img, DIM, qkv_wT, qkv_b, nullptr, 0, qkvb, 768, 256);

  attn_kernel<<<4096, 64, 0, stream>>>(qkvb, lepe_w, lepe_b, localb);
  convloc_kernel<<<2048, 256, 0, stream>>>(img, conv_w, localb);

  dim3 gp(2, 128);
  gemm8_kernel<1, false><<<gp, 512, 0, stream>>>(localb, DIM, proj_wT, proj_b, x, DIM, xa, DIM, 512);

  ln_kernel<<<8192, 256, 0, stream>>>(xa, n2g, n2b, y);

  dim3 g1(8, 128);
  gemm8_kernel<2, true><<<g1, 512, 0, stream>>>(y, DIM, fc1_wT, fc1_b, nullptr, 0, h, 2048, 512);

  dim3 g2(2, 128);
  gemm8_kernel<1, false><<<g2, 512, 0, stream>>>(h, 2048, fc2_wT, fc2_b, xa, DIM, out, DIM, 2048);
}

// Round 8
// 444.641 us; speedup vs baseline: 1.3452x; 1.0105x over previous
//
#include <hip/hip_runtime.h>
#include <cstdint>
#include <cstddef>

typedef unsigned short u16;
typedef __attribute__((ext_vector_type(8))) short short8;
typedef __attribute__((ext_vector_type(4))) float f32x4;

#define DIM 512
#define C2  256
#define HD  32
#define SCALE_Q 0.17677669529663689f

__device__ __forceinline__ float bf2f(u16 u){ return __uint_as_float(((unsigned)u) << 16); }
__device__ __forceinline__ u16 f2bf(float f){
  unsigned u = __float_as_uint(f);
  unsigned r = (u + 0x7FFFu + ((u >> 16) & 1u)) >> 16;
  return (u16)r;
}

__device__ __forceinline__ f32x4 mfma16(short8 a, short8 b, f32x4 c){
  return __builtin_amdgcn_mfma_f32_16x16x32_bf16(a, b, c, 0, 0, 0);
}

// async global->LDS, 16 bytes per lane; LDS dest is wave-uniform base (+lane*16 implied)
__device__ __forceinline__ void gload16(const u16* g, u16* l){
  __builtin_amdgcn_global_load_lds((const __attribute__((address_space(1))) void*)g,
                                   (__attribute__((address_space(3))) void*)l, 16, 0, 0);
}

// fast gelu: v * sigmoid(1.702 v)  (6 VALU ops; |err| vs exact erf-gelu <= ~0.02 abs)
__device__ __forceinline__ float gelu_f(float v){
  float e = __expf(-1.702f * v);
  return v * __builtin_amdgcn_rcpf(1.0f + e);
}

// ---------------- coalesced weight transpose + fp32->bf16 via LDS tile ----------------
// WT[n][k] = bf16(W[k][n]); grid (N/32, K/32), block 256
__global__ __launch_bounds__(256) void transpose_kernel(const float* __restrict__ W,
                                                        u16* __restrict__ WT, int K, int N){
  __shared__ u16 Tl[32][33];
  int n0 = blockIdx.x * 32, k0 = blockIdx.y * 32;
  int tx = threadIdx.x & 31, ty = threadIdx.x >> 5;   // ty 0..7
#pragma unroll
  for (int i = 0; i < 4; i++){
    int k = ty * 4 + i;
    Tl[k][tx] = f2bf(W[(size_t)(k0 + k) * N + n0 + tx]);
  }
  __syncthreads();
#pragma unroll
  for (int i = 0; i < 4; i++){
    int n = ty * 4 + i;
    WT[(size_t)(n0 + n) * K + k0 + tx] = Tl[tx][n];
  }
}

// ---------------- LayerNorm over last dim (512), one wave per row; fp32 in -> bf16 out ----------------
__global__ __launch_bounds__(256) void ln_kernel(const float* __restrict__ x, const float* __restrict__ g,
                                                 const float* __restrict__ bta, u16* __restrict__ out){
  int row  = blockIdx.x * 4 + (threadIdx.x >> 6);
  int lane = threadIdx.x & 63;
  size_t base = (size_t)row * DIM + lane * 8;
  float4 v0 = *(const float4*)(x + base);
  float4 v1 = *(const float4*)(x + base + 4);
  float f[8] = {v0.x, v0.y, v0.z, v0.w, v1.x, v1.y, v1.z, v1.w};
  float s = 0.f;
#pragma unroll
  for (int j = 0; j < 8; j++) s += f[j];
#pragma unroll
  for (int m = 1; m < 64; m <<= 1) s += __shfl_xor(s, m, 64);
  float mean = s * (1.0f / DIM);
  float vs = 0.f;
#pragma unroll
  for (int j = 0; j < 8; j++){ float d = f[j] - mean; vs += d * d; }
#pragma unroll
  for (int m = 1; m < 64; m <<= 1) vs += __shfl_xor(vs, m, 64);
  float rstd = rsqrtf(vs * (1.0f / DIM) + 1e-5f);
  float4 g0 = *(const float4*)(g + lane * 8);
  float4 g1 = *(const float4*)(g + lane * 8 + 4);
  float4 b0 = *(const float4*)(bta + lane * 8);
  float4 b1 = *(const float4*)(bta + lane * 8 + 4);
  float gg[8] = {g0.x, g0.y, g0.z, g0.w, g1.x, g1.y, g1.z, g1.w};
  float bb[8] = {b0.x, b0.y, b0.z, b0.w, b1.x, b1.y, b1.z, b1.w};
  short8 o;
#pragma unroll
  for (int j = 0; j < 8; j++){
    float r = (f[j] - mean) * rstd * gg[j] + bb[j];
    o[j] = (short)f2bf(r);
  }
  *(short8*)(out + base) = o;
}

// ---------------- GEMM, 256x256 8-phase schedule, deep (1-tile-ahead) prefetch ----------------
// C[M x N] = A[M x K] @ W[K x N] (+bias, +epilogue)
// A bf16 row-major (lda); WT = bf16 W-transposed [N x K] row-major. K multiple of 64, NT>=4.
// 8 waves (2M x 4N), per-wave C = 128x64. BK=64 split into two K-halves (kh) of 32.
// LDS: [2 dbuf][2 kh][256 rows][32 cols] per matrix = 64 KB each, 128 KB total.
// Staging: global_load_lds w16, linear LDS dest + inverse-swizzled global source;
// reads use slot = lhi ^ ((row>>1)&3)  (bank-conflict-free, both-sides rule).
// MFMA operands SWAPPED: acc = mfma(bf, af) -> lane holds C[row = l16][col = lhi*4+i]
// => epilogue is direct float4/ushort4 stores, no LDS transpose.
// Pipeline: ALL of tile t+2 staged during tile t (B[kh0]@P2, A[kh0]@P3, B[kh1]@P4,
// A[kh1]@post-P4-close-barrier); drain vmcnt(8) -> tile t+1's 8-load batch complete,
// tile t+2's 8 loads stay in flight. Issue-to-wait distance >= 1 full tile (~5 phases).
// Stage-placement safety: each staged region's last ds_read is >=1 closing barrier
// before the stage issue (B0:P1<P2, A0:P2<P3, B1:P3<P4, A1:P4-pre<P4-close).
template<int EPI, bool OUT_BF16>
__global__ __launch_bounds__(512, 2) void gemm8_kernel(
    const u16* __restrict__ A, int lda,
    const u16* __restrict__ WT,
    const float* __restrict__ bias,
    const float* R, int ldr,
    void* Cv, int ldc, int K)
{
  __shared__ u16 Al[2][2][256 * 32];
  __shared__ u16 Bl[2][2][256 * 32];
  const int tid = threadIdx.x;
  const int l   = tid & 63;
  const int w   = tid >> 6;        // wave 0..7
  const int wr  = w >> 2;          // M half
  const int wc  = w & 3;           // N quarter
  const int l16 = l & 15, lhi = l >> 4;

  // XCD-chunked swizzle (nwg % 8 == 0 for all our grids): consecutive tiles -> same XCD L2
  const int gx = gridDim.x;
  int bid = blockIdx.y * gx + blockIdx.x;
  int nwg = gx * gridDim.y;
  int sw  = (nwg & 7) ? bid : ((bid & 7) * (nwg >> 3) + (bid >> 3));
  const int col0 = (sw % gx) * 256, row0 = (sw / gx) * 256;
  const int NT = K >> 6;

  // per-lane staging source: lane covers LDS row (w*16 + l/4), slot (l&3).
  // source col-group = slot ^ ((row>>1)&3) = (l&3) ^ ((l>>3)&3)
  const int srow = w * 16 + (l >> 2);
  const int cs   = (((l & 3) ^ ((l >> 3) & 3)) * 8);
  const u16* pA = A  + (size_t)(row0 + srow) * lda + cs;
  const u16* pB = WT + (size_t)(col0 + srow) * K  + cs;
  const size_t a128 = (size_t)128 * lda, b128 = (size_t)128 * K;

  auto stageA = [&](int tt, int hh){
    if (tt < NT){
      size_t go = (size_t)tt * 64 + (size_t)hh * 32;
      gload16(pA + go,        &Al[tt & 1][hh][(w * 16) * 32]);
      gload16(pA + a128 + go, &Al[tt & 1][hh][(128 + w * 16) * 32]);
    }
  };
  auto stageB = [&](int tt, int hh){
    if (tt < NT){
      size_t go = (size_t)tt * 64 + (size_t)hh * 32;
      gload16(pB + go,        &Bl[tt & 1][hh][(w * 16) * 32]);
      gload16(pB + b128 + go, &Bl[tt & 1][hh][(128 + w * 16) * 32]);
    }
  };

  // per-lane read offset within a [256][32] region (u16 units), slot-swizzled
  const int rdo = l16 * 32 + (lhi ^ ((l16 >> 1) & 3)) * 8;

  f32x4 acc[8][4] = {};
  short8 af[4], bf[4];

  // prologue: stage tile0 AND tile1 fully; vmcnt(8) -> tile0's 8 loads landed
  stageA(0, 0); stageB(0, 0); stageA(0, 1); stageB(0, 1);
  stageA(1, 0); stageB(1, 0); stageA(1, 1); stageB(1, 1);
  asm volatile("s_waitcnt vmcnt(8)" ::: "memory");
  __builtin_amdgcn_sched_barrier(0);
  __builtin_amdgcn_s_barrier();

#define PHASE(BC, KH, QM, STAGES) do{                                                   \
    if ((QM) == 0){                                                                     \
      _Pragma("unroll")                                                                 \
      for (int n = 0; n < 4; n++)                                                       \
        bf[n] = *(const short8*)&Bl[BC][KH][(wc * 64 + n * 16) * 32 + rdo];             \
    }                                                                                   \
    _Pragma("unroll")                                                                   \
    for (int m = 0; m < 4; m++)                                                         \
      af[m] = *(const short8*)&Al[BC][KH][(wr * 128 + (QM) * 64 + m * 16) * 32 + rdo];  \
    STAGES;                                                                             \
    __builtin_amdgcn_s_barrier();                                                       \
    asm volatile("s_waitcnt lgkmcnt(0)" ::: "memory");                                  \
    __builtin_amdgcn_sched_barrier(0);                                                  \
    __builtin_amdgcn_s_setprio(1);                                                      \
    _Pragma("unroll")                                                                   \
    for (int m = 0; m < 4; m++)                                                         \
      _Pragma("unroll")                                                                 \
      for (int n = 0; n < 4; n++)                                                       \
        acc[(QM) * 4 + m][n] = mfma16(bf[n], af[m], acc[(QM) * 4 + m][n]);              \
    __builtin_amdgcn_s_setprio(0);                                                      \
    __builtin_amdgcn_s_barrier();                                                       \
  }while(0)

  for (int t = 0; t < NT; t++){
    const int bc = t & 1;
    PHASE(bc, 0, 0, (void)0);               // P1
    PHASE(bc, 0, 1, stageB(t + 2, 0));      // P2: Bl[bc][0] last read at P1
    PHASE(bc, 1, 0, stageA(t + 2, 0));      // P3: Al[bc][0] last read at P2
    PHASE(bc, 1, 1, stageB(t + 2, 1));      // P4: Bl[bc][1] last read at P3
    stageA(t + 2, 1);                       // post-P4-close: Al[bc][1] reads all done
    if (t + 2 < NT) asm volatile("s_waitcnt vmcnt(8)" ::: "memory");
    else            asm volatile("s_waitcnt vmcnt(0)" ::: "memory");
    __builtin_amdgcn_sched_barrier(0);
    __builtin_amdgcn_s_barrier();
  }
#undef PHASE

  // ---- direct vectorized epilogue (no LDS): lane owns row = l16, cols = lhi*4+{0..3} per fragment ----
  float4 bvs[4];
#pragma unroll
  for (int n = 0; n < 4; n++)
    bvs[n] = *(const float4*)&bias[col0 + wc * 64 + n * 16 + lhi * 4];
#pragma unroll
  for (int mq = 0; mq < 8; mq++){
    int grow = row0 + wr * 128 + mq * 16 + l16;
#pragma unroll
    for (int n = 0; n < 4; n++){
      int gcol = col0 + wc * 64 + n * 16 + lhi * 4;
      float4 vv = { acc[mq][n][0] + bvs[n].x, acc[mq][n][1] + bvs[n].y,
                    acc[mq][n][2] + bvs[n].z, acc[mq][n][3] + bvs[n].w };
      if constexpr (EPI == 1){
        float4 rv = *(const float4*)&R[(size_t)grow * ldr + gcol];
        vv.x += rv.x; vv.y += rv.y; vv.z += rv.z; vv.w += rv.w;
      }
      if constexpr (EPI == 2){
        vv.x = gelu_f(vv.x); vv.y = gelu_f(vv.y); vv.z = gelu_f(vv.z); vv.w = gelu_f(vv.w);
      }
      if constexpr (OUT_BF16){
        ushort4 o4 = { f2bf(vv.x), f2bf(vv.y), f2bf(vv.z), f2bf(vv.w) };
        *(ushort4*)&((u16*)Cv)[(size_t)grow * ldc + gcol] = o4;
      } else {
        *(float4*)&((float*)Cv)[(size_t)grow * ldc + gcol] = vv;
      }
    }
  }
}

// ---------------- windowed attention + LePE, one wave per (window, head) ----------------
__global__ __launch_bounds__(64) void attn_kernel(
    const u16* __restrict__ qkv, const float* __restrict__ lw,
    const float* __restrict__ lb, u16* __restrict__ out)
{
  __shared__ float Ks[64][33];
  __shared__ float Vs[64][33];
  __shared__ float Wle[32][9];
  __shared__ float Lb[32];
  int head = blockIdx.x & 7, win = blockIdx.x >> 3;
  int wx = win & 7, wy = (win >> 3) & 7, b = win >> 6;
  int l  = threadIdx.x;           // query pixel in window
  int py = l >> 3, px = l & 7;
  size_t t = (size_t)b * 4096 + (size_t)(wy * 8 + py) * 64 + (wx * 8 + px);
  const u16* base = qkv + t * 768 + head * HD;

  float q[32];
#pragma unroll
  for (int j = 0; j < 32; j += 8){
    short8 vq = *(const short8*)(base + j);
    short8 vk = *(const short8*)(base + 256 + j);
    short8 vv = *(const short8*)(base + 512 + j);
#pragma unroll
    for (int e = 0; e < 8; e++){
      q[j + e]     = bf2f((u16)vq[e]) * SCALE_Q;
      Ks[l][j + e] = bf2f((u16)vk[e]);
      Vs[l][j + e] = bf2f((u16)vv[e]);
    }
  }
  for (int i = l; i < 288; i += 64) Wle[i / 9][i % 9] = lw[(head * 32 + i / 9) * 9 + (i % 9)];
  if (l < 32) Lb[l] = lb[head * 32 + l];
  __syncthreads();

  float sc[64];
  float mx = -1e30f;
#pragma unroll
  for (int k = 0; k < 64; k++){
    float s = 0.f;
#pragma unroll
    for (int d = 0; d < 32; d++) s += q[d] * Ks[k][d];
    sc[k] = s; mx = fmaxf(mx, s);
  }
  float sum = 0.f;
#pragma unroll
  for (int k = 0; k < 64; k++){ float e = __expf(sc[k] - mx); sc[k] = e; sum += e; }
  float inv = 1.0f / sum;
  float o[32];
#pragma unroll
  for (int d = 0; d < 32; d++) o[d] = 0.f;
#pragma unroll
  for (int k = 0; k < 64; k++){
    float p = sc[k] * inv;
#pragma unroll
    for (int d = 0; d < 32; d++) o[d] += p * Vs[k][d];
  }
  // LePE: depthwise 3x3 over the 8x8 window (zero pad at window edges)
#pragma unroll
  for (int ky = 0; ky < 3; ky++){
    int yy = py + ky - 1;
    if (yy < 0 || yy >= 8) continue;
#pragma unroll
    for (int kx = 0; kx < 3; kx++){
      int xx = px + kx - 1;
      if (xx < 0 || xx >= 8) continue;
      int kp = yy * 8 + xx;
#pragma unroll
      for (int d = 0; d < 32; d++) o[d] += Wle[d][ky * 3 + kx] * Vs[kp][d];
    }
  }
  u16* op = out + t * DIM + head * HD;
#pragma unroll
  for (int d = 0; d < 32; d += 4){
    ushort4 o4 = { f2bf(o[d] + Lb[d]), f2bf(o[d + 1] + Lb[d + 1]),
                   f2bf(o[d + 2] + Lb[d + 2]), f2bf(o[d + 3] + Lb[d + 3]) };
    *(ushort4*)&op[d] = o4;
  }
}

// ---------------- full-image depthwise 3x3 on img[..., 256:], thread = channel ----------------
__global__ __launch_bounds__(256) void convloc_kernel(const u16* __restrict__ img,
    const float* __restrict__ w, u16* __restrict__ out){
  int c  = threadIdx.x;
  int pg = blockIdx.x;            // 2048 groups of 16 pixels
  int b  = pg >> 8;
  int p0 = (pg & 255) * 16;
  float wt[9];
#pragma unroll
  for (int i = 0; i < 9; i++) wt[i] = w[c * 9 + i];
  for (int pi = 0; pi < 16; pi++){
    int p = p0 + pi;
    int y = p >> 6, x = p & 63;
    float acc = 0.f;
#pragma unroll
    for (int ky = 0; ky < 3; ky++){
      int yy = y + ky - 1;
      if (yy < 0 || yy >= 64) continue;
#pragma unroll
      for (int kx = 0; kx < 3; kx++){
        int xx = x + kx - 1;
        if (xx < 0 || xx >= 64) continue;
        acc += wt[ky * 3 + kx] * bf2f(img[((size_t)b * 4096 + yy * 64 + xx) * DIM + C2 + c]);
      }
    }
    out[((size_t)b * 4096 + p) * DIM + C2 + c] = f2bf(acc);
  }
}

extern "C" void kernel_launch(void* const* d_in, const int* in_sizes, int n_in,
                              void* d_out, int out_size, void* d_ws, size_t ws_size,
                              hipStream_t stream){
  const float* x      = (const float*)d_in[0];
  const float* n1g    = (const float*)d_in[1];
  const float* n1b    = (const float*)d_in[2];
  const float* qkv_w  = (const float*)d_in[3];
  const float* qkv_b  = (const float*)d_in[4];
  const float* lepe_w = (const float*)d_in[5];
  const float* lepe_b = (const float*)d_in[6];
  const float* conv_w = (const float*)d_in[7];
  const float* proj_w = (const float*)d_in[8];
  const float* proj_b = (const float*)d_in[9];
  const float* n2g    = (const float*)d_in[10];
  const float* n2b    = (const float*)d_in[11];
  const float* fc1_w  = (const float*)d_in[12];
  const float* fc1_b  = (const float*)d_in[13];
  const float* fc2_w  = (const float*)d_in[14];
  const float* fc2_b  = (const float*)d_in[15];
  float* out = (float*)d_out;

  char* ws = (char*)d_ws;
  u16* img     = (u16*)(ws + 0);
  u16* qkvb    = (u16*)(ws + 33554432ull);
  u16* localb  = (u16*)(ws + 83886080ull);
  u16* y       = (u16*)(ws + 0);
  u16* h       = (u16*)(ws + 33554432ull);
  u16* qkv_wT  = (u16*)(ws + 167772160ull);
  u16* proj_wT = (u16*)(ws + 167772160ull + 393216ull);
  u16* fc1_wT  = (u16*)(ws + 167772160ull + 393216ull + 524288ull);
  u16* fc2_wT  = (u16*)(ws + 167772160ull + 393216ull + 524288ull + 2097152ull);
  float* xa    = (float*)d_out;

  { dim3 g(24, 8);  transpose_kernel<<<g, 256, 0, stream>>>(qkv_w,  qkv_wT,  256, 768);  }
  { dim3 g(16, 16); transpose_kernel<<<g, 256, 0, stream>>>(proj_w, proj_wT, 512, 512);  }
  { dim3 g(64, 16); transpose_kernel<<<g, 256, 0, stream>>>(fc1_w,  fc1_wT,  512, 2048); }
  { dim3 g(16, 64); transpose_kernel<<<g, 256, 0, stream>>>(fc2_w,  fc2_wT,  2048, 512); }

  ln_kernel<<<8192, 256, 0, stream>>>(x, n1g, n1b, img);

  dim3 gq(3, 128);   // x = col-blocks (256 wide), y = row-blocks
  gemm8_kernel<0, true><<<gq, 512, 0, stream>>>(img, DIM, qkv_wT, qkv_b, nullptr, 0, qkvb, 768, 256);

  attn_kernel<<<4096, 64, 0, stream>>>(qkvb, lepe_w, lepe_b, localb);
  convloc_kernel<<<2048, 256, 0, stream>>>(img, conv_w, localb);

  dim3 gp(2, 128);
  gemm8_kernel<1, false><<<gp, 512, 0, stream>>>(localb, DIM, proj_wT, proj_b, x, DIM, xa, DIM, 512);

  ln_kernel<<<8192, 256, 0, stream>>>(xa, n2g, n2b, y);

  dim3 g1(8, 128);
  gemm8_kernel<2, true><<<g1, 512, 0, stream>>>(y, DIM, fc1_wT, fc1_b, nullptr, 0, h, 2048, 512);

  dim3 g2(2, 128);
  gemm8_kernel<1, false><<<g2, 512, 0, stream>>>(h, 2048, fc2_wT, fc2_b, xa, DIM, out, DIM, 2048);
}